// Round 1
// baseline (774.221 us; speedup 1.0000x reference)
//
#include <hip/hip_runtime.h>
#include <hip/hip_bf16.h>
#include <stdint.h>

using bf16 = __hip_bfloat16;
typedef short s16x8 __attribute__((ext_vector_type(8)));
typedef float f32x4 __attribute__((ext_vector_type(4)));

#define NB 4
#define NS 1024
#define ND 768
#define NH 12
#define NE 8
#define NHID 3072
#define NTOK 4096
#define NASSIGN 8192

__device__ __forceinline__ float bf2f(bf16 v){ return __bfloat162float(v); }
__device__ __forceinline__ bf16 f2bf(float v){ return __float2bfloat16(v); }

__device__ __forceinline__ void gload_lds16(const bf16* g, bf16* l){
  __builtin_amdgcn_global_load_lds((const __attribute__((address_space(1))) void*)g,
                                   (__attribute__((address_space(3))) void*)l, 16, 0, 0);
}

// ---------------- transpose + fp32->bf16 convert: src [bz][K][N] -> dst [bz][N][K]
__global__ void transpose_convert_kernel(const float* __restrict__ src, bf16* __restrict__ dst,
                                         int K, int N){
  __shared__ float tile[32][33];
  int bz = blockIdx.z;
  src += (size_t)bz * K * N;
  dst += (size_t)bz * N * K;
  int n0 = blockIdx.x * 32, k0 = blockIdx.y * 32;
  int tx = threadIdx.x & 31, ty = threadIdx.x >> 5; // ty in 0..7
  #pragma unroll
  for (int i = 0; i < 4; i++){
    int k = ty + i * 8;
    tile[k][tx] = src[(size_t)(k0 + k) * N + n0 + tx];
  }
  __syncthreads();
  #pragma unroll
  for (int i = 0; i < 4; i++){
    int n = ty + i * 8;
    dst[(size_t)(n0 + n) * K + k0 + tx] = f2bf(tile[tx][n]);
  }
}

// ---------------- concat 3 bias vectors [768] -> [2304]
__global__ void concat3_kernel(const float* __restrict__ a, const float* __restrict__ b,
                               const float* __restrict__ c, float* __restrict__ out){
  int i = blockIdx.x * 256 + threadIdx.x;
  if (i >= 3 * ND) return;
  float v = (i < ND) ? a[i] : (i < 2 * ND ? b[i - ND] : c[i - 2 * ND]);
  out[i] = v;
}

// ---------------- LayerNorm row kernel (768 per row, 256 threads)
template<bool OF, bool OB>
__global__ void ln_kernel(const float* __restrict__ in, const float* __restrict__ g,
                          const float* __restrict__ bb, float* __restrict__ of,
                          bf16* __restrict__ ob){
  int row = blockIdx.x, t = threadIdx.x;
  const float* x = in + (size_t)row * ND;
  float v[3]; float s = 0.f, sq = 0.f;
  #pragma unroll
  for (int i = 0; i < 3; i++){ v[i] = x[t + i * 256]; s += v[i]; sq += v[i] * v[i]; }
  __shared__ float rs[4], rq[4];
  #pragma unroll
  for (int d = 32; d >= 1; d >>= 1){ s += __shfl_xor(s, d); sq += __shfl_xor(sq, d); }
  int w = t >> 6;
  if ((t & 63) == 0){ rs[w] = s; rq[w] = sq; }
  __syncthreads();
  s = rs[0] + rs[1] + rs[2] + rs[3];
  sq = rq[0] + rq[1] + rq[2] + rq[3];
  float mean = s * (1.f / ND);
  float var = sq * (1.f / ND) - mean * mean;
  float rstd = rsqrtf(var + 1e-5f);
  #pragma unroll
  for (int i = 0; i < 3; i++){
    int idx = t + i * 256;
    float y = (v[i] - mean) * rstd * g[idx] + bb[idx];
    if (OF) of[(size_t)row * ND + idx] = y;
    if (OB) ob[(size_t)row * ND + idx] = f2bf(y);
  }
}

// ---------------- GEMM: C[M][N] = A[M][K] @ Bt[N][K]^T + bias, m97-style 128x128xBK32
template<bool GATHER, bool RELU, bool OUT_BF16, bool RESID, bool SEG>
__global__ __launch_bounds__(256, 2)
void gemm_bt_kernel(const bf16* __restrict__ A, int ldA,
                    const bf16* __restrict__ Bt,
                    const float* __restrict__ bias,
                    void* __restrict__ Cv, int ldC,
                    const float* __restrict__ resid,
                    int Mfix, int N, int K,
                    const int* __restrict__ counts, const int* __restrict__ offsets,
                    const int* __restrict__ tok){
  int ex = SEG ? blockIdx.z : 0;
  int M, rowbase;
  if (SEG){ M = counts[ex]; rowbase = offsets[ex]; }
  else    { M = Mfix;       rowbase = 0; }
  int mt = blockIdx.y, nt = blockIdx.x;
  if (mt * 128 >= M) return;
  if (SEG){ Bt += (size_t)ex * N * K; bias += (size_t)ex * N; }

  __shared__ __align__(16) bf16 sA[128 * 32];
  __shared__ __align__(16) bf16 sB[128 * 32];

  int t = threadIdx.x;
  int lane = t & 63, wv = t >> 6;
  // staging chunks: chunk c covers LDS bytes [c*16, c*16+16) == row c>>2, cols (c&3)*8..+8
  int c0 = wv * 128 + lane;           // and c0+64
  int am0 = c0 >> 2;                  // tile-local row for chunk 0; chunk1 row = am0+16
  int ak  = (c0 & 3) * 8;
  int m0g = mt * 128 + am0;      if (m0g > M - 1) m0g = M - 1;
  int m1g = mt * 128 + am0 + 16; if (m1g > M - 1) m1g = M - 1;
  size_t arow0, arow1;
  if (GATHER){ arow0 = (size_t)tok[rowbase + m0g]; arow1 = (size_t)tok[rowbase + m1g]; }
  else       { arow0 = (size_t)(rowbase + m0g);    arow1 = (size_t)(rowbase + m1g); }
  const bf16* gA0 = A + arow0 * ldA + ak;
  const bf16* gA1 = A + arow1 * ldA + ak;
  const bf16* gB0 = Bt + (size_t)(nt * 128 + am0) * K + ak;
  const bf16* gB1 = Bt + (size_t)(nt * 128 + am0 + 16) * K + ak;
  bf16* lA0 = sA + (size_t)c0 * 8;        bf16* lA1 = sA + (size_t)(c0 + 64) * 8;
  bf16* lB0 = sB + (size_t)c0 * 8;        bf16* lB1 = sB + (size_t)(c0 + 64) * 8;

  int wm = (wv >> 1) * 64, wn = (wv & 1) * 64;
  int l16 = lane & 15, q4 = lane >> 4;
  int aoff[4], boff[4];
  #pragma unroll
  for (int mi = 0; mi < 4; mi++) aoff[mi] = (wm + mi * 16 + l16) * 32 + q4 * 8;
  #pragma unroll
  for (int ni = 0; ni < 4; ni++) boff[ni] = (wn + ni * 16 + l16) * 32 + q4 * 8;

  f32x4 acc[4][4] = {};

  for (int k0 = 0; k0 < K; k0 += 32){
    gload_lds16(gA0 + k0, lA0);
    gload_lds16(gA1 + k0, lA1);
    gload_lds16(gB0 + k0, lB0);
    gload_lds16(gB1 + k0, lB1);
    __syncthreads();
    s16x8 af[4], bfr[4];
    #pragma unroll
    for (int mi = 0; mi < 4; mi++) af[mi] = *(const s16x8*)(sA + aoff[mi]);
    #pragma unroll
    for (int ni = 0; ni < 4; ni++) bfr[ni] = *(const s16x8*)(sB + boff[ni]);
    #pragma unroll
    for (int mi = 0; mi < 4; mi++)
      #pragma unroll
      for (int ni = 0; ni < 4; ni++)
        acc[mi][ni] = __builtin_amdgcn_mfma_f32_16x16x32_bf16(af[mi], bfr[ni], acc[mi][ni], 0, 0, 0);
    __syncthreads();
  }

  // epilogue: C row = rowbase + m (SEG) / m, col = nt*128 + ...
  #pragma unroll
  for (int mi = 0; mi < 4; mi++){
    #pragma unroll
    for (int ni = 0; ni < 4; ni++){
      int col = nt * 128 + wn + ni * 16 + l16;
      float bv = bias[col];
      #pragma unroll
      for (int r = 0; r < 4; r++){
        int m = mt * 128 + wm + mi * 16 + q4 * 4 + r;
        if (m < M){
          size_t crow = (size_t)(rowbase + m);
          float v = acc[mi][ni][r] + bv;
          if (RELU) v = fmaxf(v, 0.f);
          if (RESID) v += resid[crow * ldC + col];
          if (OUT_BF16) ((bf16*)Cv)[crow * ldC + col] = f2bf(v);
          else          ((float*)Cv)[crow * ldC + col] = v;
        }
      }
    }
  }
}

// ---------------- V transpose: qkv v-cols [b,s,h,d] -> vT [b,h,d,s] (bf16)
__global__ void vtrans_kernel(const bf16* __restrict__ qkv, bf16* __restrict__ vT){
  __shared__ bf16 tile[32][33];
  int bh = blockIdx.z; int b = bh / NH, h = bh % NH;
  int s0 = blockIdx.x * 32, d0 = blockIdx.y * 32;
  int tx = threadIdx.x & 31, ty = threadIdx.x >> 5;
  #pragma unroll
  for (int i = 0; i < 4; i++){
    int s = s0 + ty + i * 8;
    tile[ty + i * 8][tx] = qkv[(size_t)(b * NS + s) * 2304 + 1536 + h * 64 + d0 + tx];
  }
  __syncthreads();
  #pragma unroll
  for (int i = 0; i < 4; i++){
    int d = ty + i * 8;
    vT[((size_t)bh * 64 + d0 + d) * NS + s0 + tx] = tile[tx][d];
  }
}

// ---------------- flash attention: 1 block = (b,h,128 q rows); 4 waves x 32 rows
__global__ void flash_attn_kernel(const bf16* __restrict__ qkv, const bf16* __restrict__ vT,
                                  bf16* __restrict__ ctx){
  __shared__ __align__(16) bf16 sP[4][32 * 32];
  int qt = blockIdx.x, h = blockIdx.y, b = blockIdx.z;
  int t = threadIdx.x, lane = t & 63, wv = t >> 6;
  int l16 = lane & 15, q4 = lane >> 4;
  int q0 = qt * 128 + wv * 32;
  const size_t ldq = 2304;

  s16x8 qf[2][2];
  #pragma unroll
  for (int mi = 0; mi < 2; mi++)
    #pragma unroll
    for (int kh = 0; kh < 2; kh++)
      qf[mi][kh] = *(const s16x8*)(qkv + (size_t)(b * NS + q0 + mi * 16 + l16) * ldq
                                   + h * 64 + kh * 32 + q4 * 8);

  f32x4 O[2][4] = {};
  float ms[2][4], ls[2][4];
  #pragma unroll
  for (int mi = 0; mi < 2; mi++)
    #pragma unroll
    for (int r = 0; r < 4; r++){ ms[mi][r] = -1e30f; ls[mi][r] = 0.f; }

  int kend = qt * 128 + 128;
  const bf16* kbase = qkv + 768;
  const bf16* vtb = vT + (size_t)(b * NH + h) * 64 * NS;
  const f32x4 fzero = {0.f, 0.f, 0.f, 0.f};

  for (int key0 = 0; key0 < kend; key0 += 32){
    s16x8 kf[2][2];
    #pragma unroll
    for (int ni = 0; ni < 2; ni++)
      #pragma unroll
      for (int kh = 0; kh < 2; kh++)
        kf[ni][kh] = *(const s16x8*)(kbase + (size_t)(b * NS + key0 + ni * 16 + l16) * ldq
                                     + h * 64 + kh * 32 + q4 * 8);
    f32x4 Sf[2][2];
    #pragma unroll
    for (int mi = 0; mi < 2; mi++)
      #pragma unroll
      for (int ni = 0; ni < 2; ni++){
        Sf[mi][ni] = __builtin_amdgcn_mfma_f32_16x16x32_bf16(qf[mi][0], kf[ni][0], fzero, 0, 0, 0);
        Sf[mi][ni] = __builtin_amdgcn_mfma_f32_16x16x32_bf16(qf[mi][1], kf[ni][1], Sf[mi][ni], 0, 0, 0);
      }
    #pragma unroll
    for (int mi = 0; mi < 2; mi++){
      #pragma unroll
      for (int r = 0; r < 4; r++){
        int qrow = q0 + mi * 16 + q4 * 4 + r;
        float s0v = Sf[mi][0][r] * 0.125f; if (key0 + l16 > qrow)      s0v = -1e30f;
        float s1v = Sf[mi][1][r] * 0.125f; if (key0 + 16 + l16 > qrow) s1v = -1e30f;
        float mx = fmaxf(s0v, s1v);
        #pragma unroll
        for (int d = 8; d >= 1; d >>= 1) mx = fmaxf(mx, __shfl_xor(mx, d));
        float mold = ms[mi][r];
        float mnew = fmaxf(mold, mx);
        float alpha = __expf(mold - mnew);
        float p0 = __expf(s0v - mnew), p1 = __expf(s1v - mnew);
        float rsum = p0 + p1;
        #pragma unroll
        for (int d = 8; d >= 1; d >>= 1) rsum += __shfl_xor(rsum, d);
        ls[mi][r] = ls[mi][r] * alpha + rsum;
        ms[mi][r] = mnew;
        #pragma unroll
        for (int dt = 0; dt < 4; dt++) O[mi][dt][r] *= alpha;
        int prow = mi * 16 + q4 * 4 + r;
        sP[wv][prow * 32 + l16]      = f2bf(p0);
        sP[wv][prow * 32 + 16 + l16] = f2bf(p1);
      }
    }
    s16x8 pf[2];
    #pragma unroll
    for (int mi = 0; mi < 2; mi++)
      pf[mi] = *(const s16x8*)(&sP[wv][(mi * 16 + l16) * 32 + q4 * 8]);
    s16x8 vf[4];
    #pragma unroll
    for (int dt = 0; dt < 4; dt++)
      vf[dt] = *(const s16x8*)(vtb + (size_t)(dt * 16 + l16) * NS + key0 + q4 * 8);
    #pragma unroll
    for (int mi = 0; mi < 2; mi++)
      #pragma unroll
      for (int dt = 0; dt < 4; dt++)
        O[mi][dt] = __builtin_amdgcn_mfma_f32_16x16x32_bf16(pf[mi], vf[dt], O[mi][dt], 0, 0, 0);
  }

  #pragma unroll
  for (int mi = 0; mi < 2; mi++){
    #pragma unroll
    for (int r = 0; r < 4; r++){
      int qrow = q0 + mi * 16 + q4 * 4 + r;
      float inv = 1.f / ls[mi][r];
      #pragma unroll
      for (int dt = 0; dt < 4; dt++)
        ctx[(size_t)(b * NS + qrow) * ND + h * 64 + dt * 16 + l16] = f2bf(O[mi][dt][r] * inv);
    }
  }
}

// ---------------- gate: logits=h@gw+gb, top2, softmax weights, counts
__global__ void gate_kernel(const float* __restrict__ h, const float* __restrict__ gw,
                            const float* __restrict__ gb, int* __restrict__ ridx,
                            float* __restrict__ rw, int* __restrict__ counts){
  __shared__ float sgw[ND * NE];
  int t = threadIdx.x;
  for (int i = t; i < ND * NE; i += 256) sgw[i] = gw[i];
  __syncthreads();
  int tok = blockIdx.x * 4 + (t >> 6);
  int lane = t & 63;
  const float* hr = h + (size_t)tok * ND;
  float acc[NE] = {};
  for (int i = lane; i < ND; i += 64){
    float hv = hr[i];
    #pragma unroll
    for (int e = 0; e < NE; e++) acc[e] += hv * sgw[i * NE + e];
  }
  #pragma unroll
  for (int e = 0; e < NE; e++)
    #pragma unroll
    for (int d = 32; d >= 1; d >>= 1) acc[e] += __shfl_xor(acc[e], d);
  if (lane == 0){
    float v0 = -1e30f, v1 = -1e30f; int i0 = 0, i1 = 0;
    #pragma unroll
    for (int e = 0; e < NE; e++){
      float v = acc[e] + gb[e];
      if (v > v0){ v1 = v0; i1 = i0; v0 = v; i0 = e; }
      else if (v > v1){ v1 = v; i1 = e; }
    }
    float w0 = 1.f / (1.f + __expf(v1 - v0));
    ridx[tok * 2] = i0; ridx[tok * 2 + 1] = i1;
    rw[tok * 2] = w0;  rw[tok * 2 + 1] = 1.f - w0;
    atomicAdd(&counts[i0], 1);
    atomicAdd(&counts[i1], 1);
  }
}

__global__ void scan_kernel(const int* __restrict__ counts, int* __restrict__ offsets){
  if (threadIdx.x == 0){
    int s = 0;
    for (int e = 0; e < NE; e++){ offsets[e] = s; s += counts[e]; }
  }
}

__global__ void scatter_kernel(const int* __restrict__ ridx, const int* __restrict__ offsets,
                               int* __restrict__ cursor, int* __restrict__ tok_list,
                               int* __restrict__ slot_of){
  int tk = blockIdx.x * 256 + threadIdx.x;
  if (tk >= NASSIGN) return;
  int e = ridx[tk];
  int pos = atomicAdd(&cursor[e], 1);
  int slot = offsets[e] + pos;
  tok_list[slot] = tk >> 1;
  slot_of[tk] = slot;
}

// ---------------- combine: core = w0*e2[s0]+w1*e2[s1]; out = attn_x + LN(h+core)
__global__ void combine_kernel(const bf16* __restrict__ e2, const int* __restrict__ slot_of,
                               const float* __restrict__ rw, const float* __restrict__ hf,
                               const float* __restrict__ attn_x, const float* __restrict__ g,
                               const float* __restrict__ bb, float* __restrict__ out){
  int row = blockIdx.x, t = threadIdx.x;
  int sl0 = slot_of[row * 2], sl1 = slot_of[row * 2 + 1];
  float w0 = rw[row * 2], w1 = rw[row * 2 + 1];
  const bf16* r0 = e2 + (size_t)sl0 * ND;
  const bf16* r1 = e2 + (size_t)sl1 * ND;
  const float* hr = hf + (size_t)row * ND;
  float v[3]; float s = 0.f, sq = 0.f;
  #pragma unroll
  for (int i = 0; i < 3; i++){
    int idx = t + i * 256;
    float c = w0 * bf2f(r0[idx]) + w1 * bf2f(r1[idx]);
    float xv = hr[idx] + c;
    v[i] = xv; s += xv; sq += xv * xv;
  }
  __shared__ float rs[4], rq[4];
  #pragma unroll
  for (int d = 32; d >= 1; d >>= 1){ s += __shfl_xor(s, d); sq += __shfl_xor(sq, d); }
  int w = t >> 6;
  if ((t & 63) == 0){ rs[w] = s; rq[w] = sq; }
  __syncthreads();
  s = rs[0] + rs[1] + rs[2] + rs[3];
  sq = rq[0] + rq[1] + rq[2] + rq[3];
  float mean = s * (1.f / ND);
  float var = sq * (1.f / ND) - mean * mean;
  float rstd = rsqrtf(var + 1e-5f);
  #pragma unroll
  for (int i = 0; i < 3; i++){
    int idx = t + i * 256;
    float y = (v[i] - mean) * rstd * g[idx] + bb[idx];
    out[(size_t)row * ND + idx] = attn_x[(size_t)row * ND + idx] + y;
  }
}

// ================= host =================
extern "C" void kernel_launch(void* const* d_in, const int* in_sizes, int n_in,
                              void* d_out, int out_size, void* d_ws, size_t ws_size,
                              hipStream_t stream){
  const float* x        = (const float*)d_in[0];
  const float* ln_att_g = (const float*)d_in[2];
  const float* ln_att_b = (const float*)d_in[3];
  const float* wq = (const float*)d_in[4];  const float* bq = (const float*)d_in[5];
  const float* wk = (const float*)d_in[6];  const float* bk = (const float*)d_in[7];
  const float* wv = (const float*)d_in[8];  const float* bv = (const float*)d_in[9];
  const float* wo = (const float*)d_in[10]; const float* bo = (const float*)d_in[11];
  const float* ln_ff_g = (const float*)d_in[12];
  const float* ln_ff_b = (const float*)d_in[13];
  const float* gate_w  = (const float*)d_in[14];
  const float* gate_b  = (const float*)d_in[15];
  const float* w1 = (const float*)d_in[16]; const float* b1 = (const float*)d_in[17];
  const float* w2 = (const float*)d_in[18]; const float* b2 = (const float*)d_in[19];
  const float* moe_g = (const float*)d_in[20];
  const float* moe_b = (const float*)d_in[21];

  uint8_t* p = (uint8_t*)d_ws;
  auto alloc = [&](size_t bytes) -> void* {
    void* r = (void*)p;
    p += (bytes + 255) & ~(size_t)255;
    return r;
  };
  bf16* wqkv_t  = (bf16*)alloc((size_t)2304 * 768 * 2);
  bf16* wo_t    = (bf16*)alloc((size_t)768 * 768 * 2);
  bf16* w1_t    = (bf16*)alloc((size_t)NE * NHID * ND * 2);
  bf16* w2_t    = (bf16*)alloc((size_t)NE * ND * NHID * 2);
  float* bias_qkv = (float*)alloc(2304 * 4);
  bf16* a_bf    = (bf16*)alloc((size_t)NTOK * ND * 2);
  bf16* qkv     = (bf16*)alloc((size_t)NTOK * 2304 * 2);
  bf16* vT      = (bf16*)alloc((size_t)NB * NH * 64 * NS * 2);
  bf16* ctx     = (bf16*)alloc((size_t)NTOK * ND * 2);
  float* attn_x = (float*)alloc((size_t)NTOK * ND * 4);
  float* h_f    = (float*)alloc((size_t)NTOK * ND * 4);
  bf16* h_b     = (bf16*)alloc((size_t)NTOK * ND * 2);
  int*  ridx    = (int*)alloc(NASSIGN * 4);
  float* rwt    = (float*)alloc(NASSIGN * 4);
  int* counts   = (int*)alloc(NE * 4);
  int* offsets  = (int*)alloc(NE * 4);
  int* cursor   = (int*)alloc(NE * 4);
  int* tok_list = (int*)alloc(NASSIGN * 4);
  int* slot_of  = (int*)alloc(NASSIGN * 4);
  bf16* e1      = (bf16*)alloc((size_t)NASSIGN * NHID * 2);
  bf16* e2      = (bf16*)alloc((size_t)NASSIGN * ND * 2);

  hipMemsetAsync(counts, 0, NE * 4, stream);
  hipMemsetAsync(cursor, 0, NE * 4, stream);

  // weight prep
  transpose_convert_kernel<<<dim3(24, 24, 1), 256, 0, stream>>>(wq, wqkv_t, 768, 768);
  transpose_convert_kernel<<<dim3(24, 24, 1), 256, 0, stream>>>(wk, wqkv_t + (size_t)768 * 768, 768, 768);
  transpose_convert_kernel<<<dim3(24, 24, 1), 256, 0, stream>>>(wv, wqkv_t + (size_t)1536 * 768, 768, 768);
  transpose_convert_kernel<<<dim3(24, 24, 1), 256, 0, stream>>>(wo, wo_t, 768, 768);
  transpose_convert_kernel<<<dim3(96, 24, NE), 256, 0, stream>>>(w1, w1_t, 768, 3072);
  transpose_convert_kernel<<<dim3(24, 96, NE), 256, 0, stream>>>(w2, w2_t, 3072, 768);
  concat3_kernel<<<dim3(9), 256, 0, stream>>>(bq, bk, bv, bias_qkv);

  // attention path
  ln_kernel<false, true><<<dim3(NTOK), 256, 0, stream>>>(x, ln_att_g, ln_att_b, nullptr, a_bf);
  gemm_bt_kernel<false, false, true, false, false><<<dim3(18, 32, 1), 256, 0, stream>>>(
      a_bf, ND, wqkv_t, bias_qkv, qkv, 2304, nullptr, NTOK, 2304, ND, nullptr, nullptr, nullptr);
  vtrans_kernel<<<dim3(32, 2, NB * NH), 256, 0, stream>>>(qkv, vT);
  flash_attn_kernel<<<dim3(8, NH, NB), 256, 0, stream>>>(qkv, vT, ctx);
  gemm_bt_kernel<false, false, false, true, false><<<dim3(6, 32, 1), 256, 0, stream>>>(
      ctx, ND, wo_t, bo, attn_x, ND, x, NTOK, ND, ND, nullptr, nullptr, nullptr);

  // MoE path
  ln_kernel<true, true><<<dim3(NTOK), 256, 0, stream>>>(attn_x, ln_ff_g, ln_ff_b, h_f, h_b);
  gate_kernel<<<dim3(NTOK / 4), 256, 0, stream>>>(h_f, gate_w, gate_b, ridx, rwt, counts);
  scan_kernel<<<dim3(1), 64, 0, stream>>>(counts, offsets);
  scatter_kernel<<<dim3(NASSIGN / 256), 256, 0, stream>>>(ridx, offsets, cursor, tok_list, slot_of);
  gemm_bt_kernel<true, true, true, false, true><<<dim3(24, 32, NE), 256, 0, stream>>>(
      h_b, ND, w1_t, b1, e1, NHID, nullptr, 0, NHID, ND, counts, offsets, tok_list);
  gemm_bt_kernel<false, false, true, false, true><<<dim3(6, 32, NE), 256, 0, stream>>>(
      e1, NHID, w2_t, b2, e2, ND, nullptr, 0, ND, NHID, counts, offsets, nullptr);
  combine_kernel<<<dim3(NTOK), 256, 0, stream>>>(e2, slot_of, rwt, h_f, attn_x, moe_g, moe_b,
                                                 (float*)d_out);
}

// Round 2
// 726.766 us; speedup vs baseline: 1.0653x; 1.0653x over previous
//
#include <hip/hip_runtime.h>
#include <hip/hip_bf16.h>
#include <stdint.h>

using bf16 = __hip_bfloat16;
typedef short s16x8 __attribute__((ext_vector_type(8)));
typedef float f32x4 __attribute__((ext_vector_type(4)));

#define NB 4
#define NS 1024
#define ND 768
#define NH 12
#define NE 8
#define NHID 3072
#define NTOK 4096
#define NASSIGN 8192
#define MAXCH 72               // sum ceil(counts[e]/128) <= 64 + 8
#define MAXSLOT (MAXCH * 128)  // 9216

__device__ __forceinline__ float bf2f(bf16 v){ return __bfloat162float(v); }
__device__ __forceinline__ bf16 f2bf(float v){ return __float2bfloat16(v); }

__device__ __forceinline__ void gload_lds16(const bf16* g, bf16* l){
  __builtin_amdgcn_global_load_lds((const __attribute__((address_space(1))) void*)g,
                                   (__attribute__((address_space(3))) void*)l, 16, 0, 0);
}

// ---------------- transpose + fp32->bf16 convert: src [bz][K][N] -> dst [bz][N][K]
__global__ void transpose_convert_kernel(const float* __restrict__ src, bf16* __restrict__ dst,
                                         int K, int N){
  __shared__ float tile[32][33];
  int bz = blockIdx.z;
  src += (size_t)bz * K * N;
  dst += (size_t)bz * N * K;
  int n0 = blockIdx.x * 32, k0 = blockIdx.y * 32;
  int tx = threadIdx.x & 31, ty = threadIdx.x >> 5; // ty in 0..7
  #pragma unroll
  for (int i = 0; i < 4; i++){
    int k = ty + i * 8;
    tile[k][tx] = src[(size_t)(k0 + k) * N + n0 + tx];
  }
  __syncthreads();
  #pragma unroll
  for (int i = 0; i < 4; i++){
    int n = ty + i * 8;
    dst[(size_t)(n0 + n) * K + k0 + tx] = f2bf(tile[tx][n]);
  }
}

// ---------------- concat 3 bias vectors [768] -> [2304]
__global__ void concat3_kernel(const float* __restrict__ a, const float* __restrict__ b,
                               const float* __restrict__ c, float* __restrict__ out){
  int i = blockIdx.x * 256 + threadIdx.x;
  if (i >= 3 * ND) return;
  float v = (i < ND) ? a[i] : (i < 2 * ND ? b[i - ND] : c[i - 2 * ND]);
  out[i] = v;
}

// ---------------- LayerNorm row kernel (768 per row, 256 threads)
template<bool OF, bool OB>
__global__ void ln_kernel(const float* __restrict__ in, const float* __restrict__ g,
                          const float* __restrict__ bb, float* __restrict__ of,
                          bf16* __restrict__ ob){
  int row = blockIdx.x, t = threadIdx.x;
  const float* x = in + (size_t)row * ND;
  float v[3]; float s = 0.f, sq = 0.f;
  #pragma unroll
  for (int i = 0; i < 3; i++){ v[i] = x[t + i * 256]; s += v[i]; sq += v[i] * v[i]; }
  __shared__ float rs[4], rq[4];
  #pragma unroll
  for (int d = 32; d >= 1; d >>= 1){ s += __shfl_xor(s, d); sq += __shfl_xor(sq, d); }
  int w = t >> 6;
  if ((t & 63) == 0){ rs[w] = s; rq[w] = sq; }
  __syncthreads();
  s = rs[0] + rs[1] + rs[2] + rs[3];
  sq = rq[0] + rq[1] + rq[2] + rq[3];
  float mean = s * (1.f / ND);
  float var = sq * (1.f / ND) - mean * mean;
  float rstd = rsqrtf(var + 1e-5f);
  #pragma unroll
  for (int i = 0; i < 3; i++){
    int idx = t + i * 256;
    float y = (v[i] - mean) * rstd * g[idx] + bb[idx];
    if (OF) of[(size_t)row * ND + idx] = y;
    if (OB) ob[(size_t)row * ND + idx] = f2bf(y);
  }
}

// ---------------- GEMM: C[chunk rows][N] = A @ Bt^T + bias
// chunk-flattened grid: blockIdx.y*GROUP+g = 128-row chunk id; blockIdx.x = 128-col tile.
// Double-buffered LDS K-loop, one barrier per K-panel.
template<int GROUP, bool GATHER, bool RELU, bool OBF, bool RESID, bool SEG>
__global__ __launch_bounds__(256, 3)
void gemm_kernel(const bf16* __restrict__ A, int ldA,
                 const bf16* __restrict__ BtB,
                 const float* __restrict__ biasB,
                 void* __restrict__ Cv, int ldC,
                 const float* __restrict__ resid,
                 int N, int K,
                 const int* __restrict__ chunk_e, const int* __restrict__ tok){
  __shared__ __align__(16) bf16 sA[2][128 * 32];
  __shared__ __align__(16) bf16 sB[2][128 * 32];

  int t = threadIdx.x;
  int lane = t & 63, wv = t >> 6;
  int c0i = wv * 128 + lane;          // staging chunk id (and c0i+64)
  int r0  = c0i >> 2;                 // tile-local row of chunk0; chunk1 row = r0+16
  int kk  = (c0i & 3) * 8;
  int nt = blockIdx.x;
  int wm = (wv >> 1) * 64, wn = (wv & 1) * 64;
  int l16 = lane & 15, q4 = lane >> 4;
  int aoff[4], boff[4];
  #pragma unroll
  for (int mi = 0; mi < 4; mi++) aoff[mi] = (wm + mi * 16 + l16) * 32 + q4 * 8;
  #pragma unroll
  for (int ni = 0; ni < 4; ni++) boff[ni] = (wn + ni * 16 + l16) * 32 + q4 * 8;

  for (int g = 0; g < GROUP; g++){
    int c = blockIdx.y * GROUP + g;
    int e = 0;
    if (SEG){ e = chunk_e[c]; if (e < 0) break; }
    const bf16* Bt = SEG ? BtB + (size_t)e * N * K : BtB;
    const float* bias = SEG ? biasB + (size_t)e * N : biasB;
    size_t arow0, arow1;
    int m0 = c * 128 + r0, m1 = m0 + 16;
    if (GATHER){ arow0 = (size_t)tok[m0]; arow1 = (size_t)tok[m1]; }
    else       { arow0 = (size_t)m0;      arow1 = (size_t)m1; }
    const bf16* gA0 = A + arow0 * ldA + kk;
    const bf16* gA1 = A + arow1 * ldA + kk;
    const bf16* gB0 = Bt + (size_t)(nt * 128 + r0) * K + kk;
    const bf16* gB1 = Bt + (size_t)(nt * 128 + r0 + 16) * K + kk;

    if (g > 0) __syncthreads();  // protect LDS reuse across chunks

    f32x4 acc[4][4] = {};
    // prefetch panel 0 into buffer 0
    gload_lds16(gA0, &sA[0][(size_t)c0i * 8]);
    gload_lds16(gA1, &sA[0][(size_t)(c0i + 64) * 8]);
    gload_lds16(gB0, &sB[0][(size_t)c0i * 8]);
    gload_lds16(gB1, &sB[0][(size_t)(c0i + 64) * 8]);

    int nk = K >> 5;
    for (int ki = 0; ki < nk; ki++){
      int cur = ki & 1;
      __syncthreads();   // drains my in-flight loads (vmcnt0) + all waves arrive
      if (ki + 1 < nk){
        int nxt = cur ^ 1, off = (ki + 1) * 32;
        gload_lds16(gA0 + off, &sA[nxt][(size_t)c0i * 8]);
        gload_lds16(gA1 + off, &sA[nxt][(size_t)(c0i + 64) * 8]);
        gload_lds16(gB0 + off, &sB[nxt][(size_t)c0i * 8]);
        gload_lds16(gB1 + off, &sB[nxt][(size_t)(c0i + 64) * 8]);
      }
      s16x8 af[4], bfr[4];
      #pragma unroll
      for (int mi = 0; mi < 4; mi++) af[mi] = *(const s16x8*)(&sA[cur][0] + aoff[mi]);
      #pragma unroll
      for (int ni = 0; ni < 4; ni++) bfr[ni] = *(const s16x8*)(&sB[cur][0] + boff[ni]);
      #pragma unroll
      for (int mi = 0; mi < 4; mi++)
        #pragma unroll
        for (int ni = 0; ni < 4; ni++)
          acc[mi][ni] = __builtin_amdgcn_mfma_f32_16x16x32_bf16(af[mi], bfr[ni], acc[mi][ni], 0, 0, 0);
    }

    // epilogue: chunks are always full 128 rows (padded slot space) -> no M guard
    #pragma unroll
    for (int mi = 0; mi < 4; mi++){
      #pragma unroll
      for (int ni = 0; ni < 4; ni++){
        int col = nt * 128 + wn + ni * 16 + l16;
        float bv = bias[col];
        #pragma unroll
        for (int r = 0; r < 4; r++){
          size_t crow = (size_t)(c * 128 + wm + mi * 16 + q4 * 4 + r);
          float v = acc[mi][ni][r] + bv;
          if (RELU) v = fmaxf(v, 0.f);
          if (RESID) v += resid[crow * ldC + col];
          if (OBF) ((bf16*)Cv)[crow * ldC + col] = f2bf(v);
          else     ((float*)Cv)[crow * ldC + col] = v;
        }
      }
    }
  }
}

// ---------------- V transpose: qkv v-cols [b,s,h,d] -> vT [b,h,d,s] (bf16)
__global__ void vtrans_kernel(const bf16* __restrict__ qkv, bf16* __restrict__ vT){
  __shared__ bf16 tile[32][33];
  int bh = blockIdx.z; int b = bh / NH, h = bh % NH;
  int s0 = blockIdx.x * 32, d0 = blockIdx.y * 32;
  int tx = threadIdx.x & 31, ty = threadIdx.x >> 5;
  #pragma unroll
  for (int i = 0; i < 4; i++){
    int s = s0 + ty + i * 8;
    tile[ty + i * 8][tx] = qkv[(size_t)(b * NS + s) * 2304 + 1536 + h * 64 + d0 + tx];
  }
  __syncthreads();
  #pragma unroll
  for (int i = 0; i < 4; i++){
    int d = ty + i * 8;
    vT[((size_t)bh * 64 + d0 + d) * NS + s0 + tx] = tile[tx][d];
  }
}

// ---------------- flash attention: 1 block = (b,h,128 q rows); 4 waves x 32 rows
__global__ void flash_attn_kernel(const bf16* __restrict__ qkv, const bf16* __restrict__ vT,
                                  bf16* __restrict__ ctx){
  __shared__ __align__(16) bf16 sP[4][32 * 32];
  int qt = blockIdx.x, h = blockIdx.y, b = blockIdx.z;
  int t = threadIdx.x, lane = t & 63, wv = t >> 6;
  int l16 = lane & 15, q4 = lane >> 4;
  int q0 = qt * 128 + wv * 32;
  const size_t ldq = 2304;

  s16x8 qf[2][2];
  #pragma unroll
  for (int mi = 0; mi < 2; mi++)
    #pragma unroll
    for (int kh = 0; kh < 2; kh++)
      qf[mi][kh] = *(const s16x8*)(qkv + (size_t)(b * NS + q0 + mi * 16 + l16) * ldq
                                   + h * 64 + kh * 32 + q4 * 8);

  f32x4 O[2][4] = {};
  float ms[2][4], ls[2][4];
  #pragma unroll
  for (int mi = 0; mi < 2; mi++)
    #pragma unroll
    for (int r = 0; r < 4; r++){ ms[mi][r] = -1e30f; ls[mi][r] = 0.f; }

  int kend = qt * 128 + 128;
  const bf16* kbase = qkv + 768;
  const bf16* vtb = vT + (size_t)(b * NH + h) * 64 * NS;
  const f32x4 fzero = {0.f, 0.f, 0.f, 0.f};

  for (int key0 = 0; key0 < kend; key0 += 32){
    s16x8 kf[2][2];
    #pragma unroll
    for (int ni = 0; ni < 2; ni++)
      #pragma unroll
      for (int kh = 0; kh < 2; kh++)
        kf[ni][kh] = *(const s16x8*)(kbase + (size_t)(b * NS + key0 + ni * 16 + l16) * ldq
                                     + h * 64 + kh * 32 + q4 * 8);
    f32x4 Sf[2][2];
    #pragma unroll
    for (int mi = 0; mi < 2; mi++)
      #pragma unroll
      for (int ni = 0; ni < 2; ni++){
        Sf[mi][ni] = __builtin_amdgcn_mfma_f32_16x16x32_bf16(qf[mi][0], kf[ni][0], fzero, 0, 0, 0);
        Sf[mi][ni] = __builtin_amdgcn_mfma_f32_16x16x32_bf16(qf[mi][1], kf[ni][1], Sf[mi][ni], 0, 0, 0);
      }
    #pragma unroll
    for (int mi = 0; mi < 2; mi++){
      #pragma unroll
      for (int r = 0; r < 4; r++){
        int qrow = q0 + mi * 16 + q4 * 4 + r;
        float s0v = Sf[mi][0][r] * 0.125f; if (key0 + l16 > qrow)      s0v = -1e30f;
        float s1v = Sf[mi][1][r] * 0.125f; if (key0 + 16 + l16 > qrow) s1v = -1e30f;
        float mx = fmaxf(s0v, s1v);
        #pragma unroll
        for (int d = 8; d >= 1; d >>= 1) mx = fmaxf(mx, __shfl_xor(mx, d));
        float mold = ms[mi][r];
        float mnew = fmaxf(mold, mx);
        float alpha = __expf(mold - mnew);
        float p0 = __expf(s0v - mnew), p1 = __expf(s1v - mnew);
        float rsum = p0 + p1;
        #pragma unroll
        for (int d = 8; d >= 1; d >>= 1) rsum += __shfl_xor(rsum, d);
        ls[mi][r] = ls[mi][r] * alpha + rsum;
        ms[mi][r] = mnew;
        #pragma unroll
        for (int dt = 0; dt < 4; dt++) O[mi][dt][r] *= alpha;
        int prow = mi * 16 + q4 * 4 + r;
        sP[wv][prow * 32 + l16]      = f2bf(p0);
        sP[wv][prow * 32 + 16 + l16] = f2bf(p1);
      }
    }
    s16x8 pf[2];
    #pragma unroll
    for (int mi = 0; mi < 2; mi++)
      pf[mi] = *(const s16x8*)(&sP[wv][(mi * 16 + l16) * 32 + q4 * 8]);
    s16x8 vf[4];
    #pragma unroll
    for (int dt = 0; dt < 4; dt++)
      vf[dt] = *(const s16x8*)(vtb + (size_t)(dt * 16 + l16) * NS + key0 + q4 * 8);
    #pragma unroll
    for (int mi = 0; mi < 2; mi++)
      #pragma unroll
      for (int dt = 0; dt < 4; dt++)
        O[mi][dt] = __builtin_amdgcn_mfma_f32_16x16x32_bf16(pf[mi], vf[dt], O[mi][dt], 0, 0, 0);
  }

  #pragma unroll
  for (int mi = 0; mi < 2; mi++){
    #pragma unroll
    for (int r = 0; r < 4; r++){
      int qrow = q0 + mi * 16 + q4 * 4 + r;
      float inv = 1.f / ls[mi][r];
      #pragma unroll
      for (int dt = 0; dt < 4; dt++)
        ctx[(size_t)(b * NS + qrow) * ND + h * 64 + dt * 16 + l16] = f2bf(O[mi][dt][r] * inv);
    }
  }
}

// ---------------- gate: logits=h@gw+gb, top2, softmax weights, counts
__global__ void gate_kernel(const float* __restrict__ h, const float* __restrict__ gw,
                            const float* __restrict__ gb, int* __restrict__ ridx,
                            float* __restrict__ rw, int* __restrict__ counts){
  __shared__ float sgw[ND * NE];
  int t = threadIdx.x;
  for (int i = t; i < ND * NE; i += 256) sgw[i] = gw[i];
  __syncthreads();
  int tok = blockIdx.x * 4 + (t >> 6);
  int lane = t & 63;
  const float* hr = h + (size_t)tok * ND;
  float acc[NE] = {};
  for (int i = lane; i < ND; i += 64){
    float hv = hr[i];
    #pragma unroll
    for (int e = 0; e < NE; e++) acc[e] += hv * sgw[i * NE + e];
  }
  #pragma unroll
  for (int e = 0; e < NE; e++)
    #pragma unroll
    for (int d = 32; d >= 1; d >>= 1) acc[e] += __shfl_xor(acc[e], d);
  if (lane == 0){
    float v0 = -1e30f, v1 = -1e30f; int i0 = 0, i1 = 0;
    #pragma unroll
    for (int e = 0; e < NE; e++){
      float v = acc[e] + gb[e];
      if (v > v0){ v1 = v0; i1 = i0; v0 = v; i0 = e; }
      else if (v > v1){ v1 = v; i1 = e; }
    }
    float w0 = 1.f / (1.f + __expf(v1 - v0));
    ridx[tok * 2] = i0; ridx[tok * 2 + 1] = i1;
    rw[tok * 2] = w0;  rw[tok * 2 + 1] = 1.f - w0;
    atomicAdd(&counts[i0], 1);
    atomicAdd(&counts[i1], 1);
  }
}

// scan: padded (128-aligned) expert offsets + chunk->expert map + tok_list prefill
__global__ void scan_kernel(const int* __restrict__ counts, int* __restrict__ poff,
                            int* __restrict__ chunk_e, int* __restrict__ tok_list){
  int t = threadIdx.x;
  for (int i = t; i < MAXSLOT; i += 256) tok_list[i] = 0;
  if (t == 0){
    int s = 0, c = 0;
    for (int e = 0; e < NE; e++){
      poff[e] = s;
      int nch = (counts[e] + 127) >> 7;
      for (int i = 0; i < nch; i++) chunk_e[c++] = e;
      s += nch << 7;
    }
    for (; c < MAXCH; c++) chunk_e[c] = -1;
  }
}

__global__ void scatter_kernel(const int* __restrict__ ridx, const int* __restrict__ poff,
                               int* __restrict__ cursor, int* __restrict__ tok_list,
                               int* __restrict__ slot_of){
  int tk = blockIdx.x * 256 + threadIdx.x;
  if (tk >= NASSIGN) return;
  int e = ridx[tk];
  int pos = atomicAdd(&cursor[e], 1);
  int slot = poff[e] + pos;
  tok_list[slot] = tk >> 1;
  slot_of[tk] = slot;
}

// ---------------- combine: core = w0*e2[s0]+w1*e2[s1]; out = attn_x + LN(h+core)
__global__ void combine_kernel(const bf16* __restrict__ e2, const int* __restrict__ slot_of,
                               const float* __restrict__ rw, const float* __restrict__ hf,
                               const float* __restrict__ attn_x, const float* __restrict__ g,
                               const float* __restrict__ bb, float* __restrict__ out){
  int row = blockIdx.x, t = threadIdx.x;
  int sl0 = slot_of[row * 2], sl1 = slot_of[row * 2 + 1];
  float w0 = rw[row * 2], w1 = rw[row * 2 + 1];
  const bf16* r0 = e2 + (size_t)sl0 * ND;
  const bf16* r1 = e2 + (size_t)sl1 * ND;
  const float* hr = hf + (size_t)row * ND;
  float v[3]; float s = 0.f, sq = 0.f;
  #pragma unroll
  for (int i = 0; i < 3; i++){
    int idx = t + i * 256;
    float c = w0 * bf2f(r0[idx]) + w1 * bf2f(r1[idx]);
    float xv = hr[idx] + c;
    v[i] = xv; s += xv; sq += xv * xv;
  }
  __shared__ float rs[4], rq[4];
  #pragma unroll
  for (int d = 32; d >= 1; d >>= 1){ s += __shfl_xor(s, d); sq += __shfl_xor(sq, d); }
  int w = t >> 6;
  if ((t & 63) == 0){ rs[w] = s; rq[w] = sq; }
  __syncthreads();
  s = rs[0] + rs[1] + rs[2] + rs[3];
  sq = rq[0] + rq[1] + rq[2] + rq[3];
  float mean = s * (1.f / ND);
  float var = sq * (1.f / ND) - mean * mean;
  float rstd = rsqrtf(var + 1e-5f);
  #pragma unroll
  for (int i = 0; i < 3; i++){
    int idx = t + i * 256;
    float y = (v[i] - mean) * rstd * g[idx] + bb[idx];
    out[(size_t)row * ND + idx] = attn_x[(size_t)row * ND + idx] + y;
  }
}

// ================= host =================
extern "C" void kernel_launch(void* const* d_in, const int* in_sizes, int n_in,
                              void* d_out, int out_size, void* d_ws, size_t ws_size,
                              hipStream_t stream){
  const float* x        = (const float*)d_in[0];
  const float* ln_att_g = (const float*)d_in[2];
  const float* ln_att_b = (const float*)d_in[3];
  const float* wq = (const float*)d_in[4];  const float* bq = (const float*)d_in[5];
  const float* wk = (const float*)d_in[6];  const float* bk = (const float*)d_in[7];
  const float* wv = (const float*)d_in[8];  const float* bv = (const float*)d_in[9];
  const float* wo = (const float*)d_in[10]; const float* bo = (const float*)d_in[11];
  const float* ln_ff_g = (const float*)d_in[12];
  const float* ln_ff_b = (const float*)d_in[13];
  const float* gate_w  = (const float*)d_in[14];
  const float* gate_b  = (const float*)d_in[15];
  const float* w1 = (const float*)d_in[16]; const float* b1 = (const float*)d_in[17];
  const float* w2 = (const float*)d_in[18]; const float* b2 = (const float*)d_in[19];
  const float* moe_g = (const float*)d_in[20];
  const float* moe_b = (const float*)d_in[21];

  uint8_t* p = (uint8_t*)d_ws;
  auto alloc = [&](size_t bytes) -> void* {
    void* r = (void*)p;
    p += (bytes + 255) & ~(size_t)255;
    return r;
  };
  bf16* wqkv_t  = (bf16*)alloc((size_t)2304 * 768 * 2);
  bf16* wo_t    = (bf16*)alloc((size_t)768 * 768 * 2);
  bf16* w1_t    = (bf16*)alloc((size_t)NE * NHID * ND * 2);
  bf16* w2_t    = (bf16*)alloc((size_t)NE * ND * NHID * 2);
  float* bias_qkv = (float*)alloc(2304 * 4);
  bf16* a_bf    = (bf16*)alloc((size_t)NTOK * ND * 2);
  bf16* qkv     = (bf16*)alloc((size_t)NTOK * 2304 * 2);
  bf16* vT      = (bf16*)alloc((size_t)NB * NH * 64 * NS * 2);
  bf16* ctx     = (bf16*)alloc((size_t)NTOK * ND * 2);
  float* attn_x = (float*)alloc((size_t)NTOK * ND * 4);
  float* h_f    = (float*)alloc((size_t)NTOK * ND * 4);
  bf16* h_b     = (bf16*)alloc((size_t)NTOK * ND * 2);
  int*  ridx    = (int*)alloc(NASSIGN * 4);
  float* rwt    = (float*)alloc(NASSIGN * 4);
  int* counts   = (int*)alloc(NE * 4);
  int* poff     = (int*)alloc(NE * 4);
  int* cursor   = (int*)alloc(NE * 4);
  int* chunk_e  = (int*)alloc(MAXCH * 4);
  int* tok_list = (int*)alloc(MAXSLOT * 4);
  int* slot_of  = (int*)alloc(NASSIGN * 4);
  bf16* e1      = (bf16*)alloc((size_t)MAXSLOT * NHID * 2);
  bf16* e2      = (bf16*)alloc((size_t)MAXSLOT * ND * 2);

  hipMemsetAsync(counts, 0, NE * 4, stream);
  hipMemsetAsync(cursor, 0, NE * 4, stream);

  // weight prep
  transpose_convert_kernel<<<dim3(24, 24, 1), 256, 0, stream>>>(wq, wqkv_t, 768, 768);
  transpose_convert_kernel<<<dim3(24, 24, 1), 256, 0, stream>>>(wk, wqkv_t + (size_t)768 * 768, 768, 768);
  transpose_convert_kernel<<<dim3(24, 24, 1), 256, 0, stream>>>(wv, wqkv_t + (size_t)1536 * 768, 768, 768);
  transpose_convert_kernel<<<dim3(24, 24, 1), 256, 0, stream>>>(wo, wo_t, 768, 768);
  transpose_convert_kernel<<<dim3(96, 24, NE), 256, 0, stream>>>(w1, w1_t, 768, 3072);
  transpose_convert_kernel<<<dim3(24, 96, NE), 256, 0, stream>>>(w2, w2_t, 3072, 768);
  concat3_kernel<<<dim3(9), 256, 0, stream>>>(bq, bk, bv, bias_qkv);

  // attention path
  ln_kernel<false, true><<<dim3(NTOK), 256, 0, stream>>>(x, ln_att_g, ln_att_b, nullptr, a_bf);
  // QKV: M=4096 (32 chunks, GROUP=2 -> grid.y=16), N=2304, K=768
  gemm_kernel<2, false, false, true, false, false><<<dim3(18, 16), 256, 0, stream>>>(
      a_bf, ND, wqkv_t, bias_qkv, qkv, 2304, nullptr, 2304, ND, nullptr, nullptr);
  vtrans_kernel<<<dim3(32, 2, NB * NH), 256, 0, stream>>>(qkv, vT);
  flash_attn_kernel<<<dim3(8, NH, NB), 256, 0, stream>>>(qkv, vT, ctx);
  // O-proj: M=4096 (32 chunks, GROUP=1), N=768, K=768, +residual, fp32 out
  gemm_kernel<1, false, false, false, true, false><<<dim3(6, 32), 256, 0, stream>>>(
      ctx, ND, wo_t, bo, attn_x, ND, x, ND, ND, nullptr, nullptr);

  // MoE path
  ln_kernel<true, true><<<dim3(NTOK), 256, 0, stream>>>(attn_x, ln_ff_g, ln_ff_b, h_f, h_b);
  gate_kernel<<<dim3(NTOK / 4), 256, 0, stream>>>(h_f, gate_w, gate_b, ridx, rwt, counts);
  scan_kernel<<<dim3(1), 256, 0, stream>>>(counts, poff, chunk_e, tok_list);
  scatter_kernel<<<dim3(NASSIGN / 256), 256, 0, stream>>>(ridx, poff, cursor, tok_list, slot_of);
  // FF1: SEG+GATHER+RELU, chunks<=72 (GROUP=2 -> grid.y=36), N=3072, K=768
  gemm_kernel<2, true, true, true, false, true><<<dim3(24, 36), 256, 0, stream>>>(
      h_b, ND, w1_t, b1, e1, NHID, nullptr, NHID, ND, chunk_e, tok_list);
  // FF2: SEG, chunks<=72 (GROUP=1 -> grid.y=72), N=768, K=3072
  gemm_kernel<1, false, false, true, false, true><<<dim3(6, 72), 256, 0, stream>>>(
      e1, NHID, w2_t, b2, e2, ND, nullptr, ND, NHID, chunk_e, nullptr);
  combine_kernel<<<dim3(NTOK), 256, 0, stream>>>(e2, slot_of, rwt, h_f, attn_x, moe_g, moe_b,
                                                 (float*)d_out);
}

// Round 3
// 711.610 us; speedup vs baseline: 1.0880x; 1.0213x over previous
//
#include <hip/hip_runtime.h>
#include <hip/hip_bf16.h>
#include <stdint.h>

using bf16 = __hip_bfloat16;
typedef short s16x8 __attribute__((ext_vector_type(8)));
typedef float f32x4 __attribute__((ext_vector_type(4)));

#define NB 4
#define NS 1024
#define ND 768
#define NH 12
#define NE 8
#define NHID 3072
#define NTOK 4096
#define NASSIGN 8192
#define MAXCH 72               // sum ceil(counts[e]/128) <= 64 + 8
#define MAXSLOT (MAXCH * 128)  // 9216

__device__ __forceinline__ float bf2f(bf16 v){ return __bfloat162float(v); }
__device__ __forceinline__ bf16 f2bf(float v){ return __float2bfloat16(v); }

__device__ __forceinline__ void gload_lds16(const bf16* g, bf16* l){
  __builtin_amdgcn_global_load_lds((const __attribute__((address_space(1))) void*)g,
                                   (__attribute__((address_space(3))) void*)l, 16, 0, 0);
}

// ---------------- transpose + fp32->bf16 convert: src [bz][K][N] -> dst [bz][N][K]
__global__ void transpose_convert_kernel(const float* __restrict__ src, bf16* __restrict__ dst,
                                         int K, int N){
  __shared__ float tile[32][33];
  int bz = blockIdx.z;
  src += (size_t)bz * K * N;
  dst += (size_t)bz * N * K;
  int n0 = blockIdx.x * 32, k0 = blockIdx.y * 32;
  int tx = threadIdx.x & 31, ty = threadIdx.x >> 5; // ty in 0..7
  #pragma unroll
  for (int i = 0; i < 4; i++){
    int k = ty + i * 8;
    tile[k][tx] = src[(size_t)(k0 + k) * N + n0 + tx];
  }
  __syncthreads();
  #pragma unroll
  for (int i = 0; i < 4; i++){
    int n = ty + i * 8;
    dst[(size_t)(n0 + n) * K + k0 + tx] = f2bf(tile[tx][n]);
  }
}

// ---------------- concat 3 bias vectors [768] -> [2304]
__global__ void concat3_kernel(const float* __restrict__ a, const float* __restrict__ b,
                               const float* __restrict__ c, float* __restrict__ out){
  int i = blockIdx.x * 256 + threadIdx.x;
  if (i >= 3 * ND) return;
  float v = (i < ND) ? a[i] : (i < 2 * ND ? b[i - ND] : c[i - 2 * ND]);
  out[i] = v;
}

// ---------------- LayerNorm row kernel (768 per row, 256 threads)
template<bool OF, bool OB>
__global__ void ln_kernel(const float* __restrict__ in, const float* __restrict__ g,
                          const float* __restrict__ bb, float* __restrict__ of,
                          bf16* __restrict__ ob){
  int row = blockIdx.x, t = threadIdx.x;
  const float* x = in + (size_t)row * ND;
  float v[3]; float s = 0.f, sq = 0.f;
  #pragma unroll
  for (int i = 0; i < 3; i++){ v[i] = x[t + i * 256]; s += v[i]; sq += v[i] * v[i]; }
  __shared__ float rs[4], rq[4];
  #pragma unroll
  for (int d = 32; d >= 1; d >>= 1){ s += __shfl_xor(s, d); sq += __shfl_xor(sq, d); }
  int w = t >> 6;
  if ((t & 63) == 0){ rs[w] = s; rq[w] = sq; }
  __syncthreads();
  s = rs[0] + rs[1] + rs[2] + rs[3];
  sq = rq[0] + rq[1] + rq[2] + rq[3];
  float mean = s * (1.f / ND);
  float var = sq * (1.f / ND) - mean * mean;
  float rstd = rsqrtf(var + 1e-5f);
  #pragma unroll
  for (int i = 0; i < 3; i++){
    int idx = t + i * 256;
    float y = (v[i] - mean) * rstd * g[idx] + bb[idx];
    if (OF) of[(size_t)row * ND + idx] = y;
    if (OB) ob[(size_t)row * ND + idx] = f2bf(y);
  }
}

// ---------------- GEMM: C[chunk rows][N] = A @ Bt^T + bias
template<int GROUP, bool GATHER, bool RELU, bool OBF, bool RESID, bool SEG>
__global__ __launch_bounds__(256, 3)
void gemm_kernel(const bf16* __restrict__ A, int ldA,
                 const bf16* __restrict__ BtB,
                 const float* __restrict__ biasB,
                 void* __restrict__ Cv, int ldC,
                 const float* __restrict__ resid,
                 int N, int K,
                 const int* __restrict__ chunk_e, const int* __restrict__ tok){
  __shared__ __align__(16) bf16 sA[2][128 * 32];
  __shared__ __align__(16) bf16 sB[2][128 * 32];

  int t = threadIdx.x;
  int lane = t & 63, wv = t >> 6;
  int c0i = wv * 128 + lane;          // staging chunk id (and c0i+64)
  int r0  = c0i >> 2;                 // tile-local row of chunk0; chunk1 row = r0+16
  int kk  = (c0i & 3) * 8;
  int nt = blockIdx.x;
  int wm = (wv >> 1) * 64, wn = (wv & 1) * 64;
  int l16 = lane & 15, q4 = lane >> 4;
  int aoff[4], boff[4];
  #pragma unroll
  for (int mi = 0; mi < 4; mi++) aoff[mi] = (wm + mi * 16 + l16) * 32 + q4 * 8;
  #pragma unroll
  for (int ni = 0; ni < 4; ni++) boff[ni] = (wn + ni * 16 + l16) * 32 + q4 * 8;

  for (int g = 0; g < GROUP; g++){
    int c = blockIdx.y * GROUP + g;
    int e = 0;
    if (SEG){ e = chunk_e[c]; if (e < 0) break; }
    const bf16* Bt = SEG ? BtB + (size_t)e * N * K : BtB;
    const float* bias = SEG ? biasB + (size_t)e * N : biasB;
    size_t arow0, arow1;
    int m0 = c * 128 + r0, m1 = m0 + 16;
    if (GATHER){ arow0 = (size_t)tok[m0]; arow1 = (size_t)tok[m1]; }
    else       { arow0 = (size_t)m0;      arow1 = (size_t)m1; }
    const bf16* gA0 = A + arow0 * ldA + kk;
    const bf16* gA1 = A + arow1 * ldA + kk;
    const bf16* gB0 = Bt + (size_t)(nt * 128 + r0) * K + kk;
    const bf16* gB1 = Bt + (size_t)(nt * 128 + r0 + 16) * K + kk;

    if (g > 0) __syncthreads();  // protect LDS reuse across chunks

    f32x4 acc[4][4] = {};
    gload_lds16(gA0, &sA[0][(size_t)c0i * 8]);
    gload_lds16(gA1, &sA[0][(size_t)(c0i + 64) * 8]);
    gload_lds16(gB0, &sB[0][(size_t)c0i * 8]);
    gload_lds16(gB1, &sB[0][(size_t)(c0i + 64) * 8]);

    int nk = K >> 5;
    for (int ki = 0; ki < nk; ki++){
      int cur = ki & 1;
      __syncthreads();
      if (ki + 1 < nk){
        int nxt = cur ^ 1, off = (ki + 1) * 32;
        gload_lds16(gA0 + off, &sA[nxt][(size_t)c0i * 8]);
        gload_lds16(gA1 + off, &sA[nxt][(size_t)(c0i + 64) * 8]);
        gload_lds16(gB0 + off, &sB[nxt][(size_t)c0i * 8]);
        gload_lds16(gB1 + off, &sB[nxt][(size_t)(c0i + 64) * 8]);
      }
      s16x8 af[4], bfr[4];
      #pragma unroll
      for (int mi = 0; mi < 4; mi++) af[mi] = *(const s16x8*)(&sA[cur][0] + aoff[mi]);
      #pragma unroll
      for (int ni = 0; ni < 4; ni++) bfr[ni] = *(const s16x8*)(&sB[cur][0] + boff[ni]);
      #pragma unroll
      for (int mi = 0; mi < 4; mi++)
        #pragma unroll
        for (int ni = 0; ni < 4; ni++)
          acc[mi][ni] = __builtin_amdgcn_mfma_f32_16x16x32_bf16(af[mi], bfr[ni], acc[mi][ni], 0, 0, 0);
    }

    #pragma unroll
    for (int mi = 0; mi < 4; mi++){
      #pragma unroll
      for (int ni = 0; ni < 4; ni++){
        int col = nt * 128 + wn + ni * 16 + l16;
        float bv = bias[col];
        #pragma unroll
        for (int r = 0; r < 4; r++){
          size_t crow = (size_t)(c * 128 + wm + mi * 16 + q4 * 4 + r);
          float v = acc[mi][ni][r] + bv;
          if (RELU) v = fmaxf(v, 0.f);
          if (RESID) v += resid[crow * ldC + col];
          if (OBF) ((bf16*)Cv)[crow * ldC + col] = f2bf(v);
          else     ((float*)Cv)[crow * ldC + col] = v;
        }
      }
    }
  }
}

// ---------------- V transpose: qkv v-cols [b,s,h,d] -> vT [b,h,d,s] (bf16)
__global__ void vtrans_kernel(const bf16* __restrict__ qkv, bf16* __restrict__ vT){
  __shared__ bf16 tile[32][33];
  int bh = blockIdx.z; int b = bh / NH, h = bh % NH;
  int s0 = blockIdx.x * 32, d0 = blockIdx.y * 32;
  int tx = threadIdx.x & 31, ty = threadIdx.x >> 5;
  #pragma unroll
  for (int i = 0; i < 4; i++){
    int s = s0 + ty + i * 8;
    tile[ty + i * 8][tx] = qkv[(size_t)(b * NS + s) * 2304 + 1536 + h * 64 + d0 + tx];
  }
  __syncthreads();
  #pragma unroll
  for (int i = 0; i < 4; i++){
    int d = ty + i * 8;
    vT[((size_t)bh * 64 + d0 + d) * NS + s0 + tx] = tile[tx][d];
  }
}

// ---------------- flash attention v2: wave = 16 q-rows, Bc=64 keys/iter
// block = 4 waves = 64 q-rows; grid (16, NH, NB) = 768 blocks.
#define SPAD 72   // sP row stride in elems (144 B = 9*16 B: b128-aligned, conflict-free)
__global__ __launch_bounds__(256, 3)
void flash_attn_kernel(const bf16* __restrict__ qkv, const bf16* __restrict__ vT,
                       bf16* __restrict__ ctx){
  __shared__ __align__(16) bf16 sP[4][16 * SPAD];
  int qt = blockIdx.x, h = blockIdx.y, b = blockIdx.z;
  int t = threadIdx.x, lane = t & 63, wv = t >> 6;
  int l16 = lane & 15, q4 = lane >> 4;
  int q0 = qt * 64 + wv * 16;               // this wave's 16 q-rows
  const size_t ldq = 2304;
  const bf16* qbase = qkv + (size_t)(b * NS) * ldq + h * 64;
  const bf16* kbase = qbase + 768;
  const bf16* vtb = vT + (size_t)(b * NH + h) * 64 * NS;
  bf16* sPw = &sP[wv][0];
  const f32x4 fzero = {0.f, 0.f, 0.f, 0.f};

  s16x8 qf[2];
  #pragma unroll
  for (int kh = 0; kh < 2; kh++)
    qf[kh] = *(const s16x8*)(qbase + (size_t)(q0 + l16) * ldq + kh * 32 + q4 * 8);

  f32x4 O[4] = {};
  float ms[4], ls[4];
  #pragma unroll
  for (int r = 0; r < 4; r++){ ms[r] = -1e30f; ls[r] = 0.f; }

  int kend = q0 + 16;  // need keys <= q0+15
  for (int key0 = 0; key0 < kend; key0 += 64){
    // K fragments: 4 ni x 2 kh
    s16x8 kf[4][2];
    #pragma unroll
    for (int ni = 0; ni < 4; ni++)
      #pragma unroll
      for (int kh = 0; kh < 2; kh++)
        kf[ni][kh] = *(const s16x8*)(kbase + (size_t)(key0 + ni * 16 + l16) * ldq + kh * 32 + q4 * 8);
    f32x4 Sf[4];
    #pragma unroll
    for (int ni = 0; ni < 4; ni++){
      Sf[ni] = __builtin_amdgcn_mfma_f32_16x16x32_bf16(qf[0], kf[ni][0], fzero, 0, 0, 0);
      Sf[ni] = __builtin_amdgcn_mfma_f32_16x16x32_bf16(qf[1], kf[ni][1], Sf[ni], 0, 0, 0);
    }
    // V fragments early (independent of softmax -> latency hides under it)
    s16x8 vf[4][2];
    #pragma unroll
    for (int dt = 0; dt < 4; dt++)
      #pragma unroll
      for (int kh = 0; kh < 2; kh++)
        vf[dt][kh] = *(const s16x8*)(vtb + (size_t)(dt * 16 + l16) * NS + key0 + kh * 32 + q4 * 8);

    bool need_mask = (key0 + 63 >= q0);  // wave-uniform
    #pragma unroll
    for (int r = 0; r < 4; r++){
      int qrow = q0 + q4 * 4 + r;
      float sv[4];
      #pragma unroll
      for (int ni = 0; ni < 4; ni++){
        sv[ni] = Sf[ni][r] * 0.125f;
        if (need_mask && (key0 + ni * 16 + l16 > qrow)) sv[ni] = -1e30f;
      }
      float mx = fmaxf(fmaxf(sv[0], sv[1]), fmaxf(sv[2], sv[3]));
      #pragma unroll
      for (int d = 8; d >= 1; d >>= 1) mx = fmaxf(mx, __shfl_xor(mx, d));
      float mnew = fmaxf(ms[r], mx);
      float alpha = __expf(ms[r] - mnew);
      float p[4], psum = 0.f;
      #pragma unroll
      for (int ni = 0; ni < 4; ni++){ p[ni] = __expf(sv[ni] - mnew); psum += p[ni]; }
      #pragma unroll
      for (int d = 8; d >= 1; d >>= 1) psum += __shfl_xor(psum, d);
      ls[r] = ls[r] * alpha + psum;
      ms[r] = mnew;
      #pragma unroll
      for (int dt = 0; dt < 4; dt++) O[dt][r] *= alpha;
      int prow = q4 * 4 + r;
      #pragma unroll
      for (int ni = 0; ni < 4; ni++)
        sPw[prow * SPAD + ni * 16 + l16] = f2bf(p[ni]);
    }
    // P A-fragments from LDS (wave-private; lgkmcnt only, no barrier)
    s16x8 pf[2];
    #pragma unroll
    for (int kh = 0; kh < 2; kh++)
      pf[kh] = *(const s16x8*)(sPw + l16 * SPAD + kh * 32 + q4 * 8);
    #pragma unroll
    for (int dt = 0; dt < 4; dt++){
      O[dt] = __builtin_amdgcn_mfma_f32_16x16x32_bf16(pf[0], vf[dt][0], O[dt], 0, 0, 0);
      O[dt] = __builtin_amdgcn_mfma_f32_16x16x32_bf16(pf[1], vf[dt][1], O[dt], 0, 0, 0);
    }
  }

  #pragma unroll
  for (int r = 0; r < 4; r++){
    float inv = 1.f / ls[r];
    int qrow = q0 + q4 * 4 + r;
    #pragma unroll
    for (int dt = 0; dt < 4; dt++)
      ctx[(size_t)(b * NS + qrow) * ND + h * 64 + dt * 16 + l16] = f2bf(O[dt][r] * inv);
  }
}

// ---------------- gate: logits=h@gw+gb, top2, softmax weights, counts
__global__ void gate_kernel(const float* __restrict__ h, const float* __restrict__ gw,
                            const float* __restrict__ gb, int* __restrict__ ridx,
                            float* __restrict__ rw, int* __restrict__ counts){
  __shared__ float sgw[ND * NE];
  int t = threadIdx.x;
  for (int i = t; i < ND * NE; i += 256) sgw[i] = gw[i];
  __syncthreads();
  int tok = blockIdx.x * 4 + (t >> 6);
  int lane = t & 63;
  const float* hr = h + (size_t)tok * ND;
  float acc[NE] = {};
  for (int i = lane; i < ND; i += 64){
    float hv = hr[i];
    #pragma unroll
    for (int e = 0; e < NE; e++) acc[e] += hv * sgw[i * NE + e];
  }
  #pragma unroll
  for (int e = 0; e < NE; e++)
    #pragma unroll
    for (int d = 32; d >= 1; d >>= 1) acc[e] += __shfl_xor(acc[e], d);
  if (lane == 0){
    float v0 = -1e30f, v1 = -1e30f; int i0 = 0, i1 = 0;
    #pragma unroll
    for (int e = 0; e < NE; e++){
      float v = acc[e] + gb[e];
      if (v > v0){ v1 = v0; i1 = i0; v0 = v; i0 = e; }
      else if (v > v1){ v1 = v; i1 = e; }
    }
    float w0 = 1.f / (1.f + __expf(v1 - v0));
    ridx[tok * 2] = i0; ridx[tok * 2 + 1] = i1;
    rw[tok * 2] = w0;  rw[tok * 2 + 1] = 1.f - w0;
    atomicAdd(&counts[i0], 1);
    atomicAdd(&counts[i1], 1);
  }
}

// scan: padded (128-aligned) expert offsets + chunk->expert map + tok_list prefill
__global__ void scan_kernel(const int* __restrict__ counts, int* __restrict__ poff,
                            int* __restrict__ chunk_e, int* __restrict__ tok_list){
  int t = threadIdx.x;
  for (int i = t; i < MAXSLOT; i += 256) tok_list[i] = 0;
  if (t == 0){
    int s = 0, c = 0;
    for (int e = 0; e < NE; e++){
      poff[e] = s;
      int nch = (counts[e] + 127) >> 7;
      for (int i = 0; i < nch; i++) chunk_e[c++] = e;
      s += nch << 7;
    }
    for (; c < MAXCH; c++) chunk_e[c] = -1;
  }
}

__global__ void scatter_kernel(const int* __restrict__ ridx, const int* __restrict__ poff,
                               int* __restrict__ cursor, int* __restrict__ tok_list,
                               int* __restrict__ slot_of){
  int tk = blockIdx.x * 256 + threadIdx.x;
  if (tk >= NASSIGN) return;
  int e = ridx[tk];
  int pos = atomicAdd(&cursor[e], 1);
  int slot = poff[e] + pos;
  tok_list[slot] = tk >> 1;
  slot_of[tk] = slot;
}

// ---------------- combine: core = w0*e2[s0]+w1*e2[s1]; out = attn_x + LN(h+core)
__global__ void combine_kernel(const bf16* __restrict__ e2, const int* __restrict__ slot_of,
                               const float* __restrict__ rw, const float* __restrict__ hf,
                               const float* __restrict__ attn_x, const float* __restrict__ g,
                               const float* __restrict__ bb, float* __restrict__ out){
  int row = blockIdx.x, t = threadIdx.x;
  int sl0 = slot_of[row * 2], sl1 = slot_of[row * 2 + 1];
  float w0 = rw[row * 2], w1 = rw[row * 2 + 1];
  const bf16* r0 = e2 + (size_t)sl0 * ND;
  const bf16* r1 = e2 + (size_t)sl1 * ND;
  const float* hr = hf + (size_t)row * ND;
  float v[3]; float s = 0.f, sq = 0.f;
  #pragma unroll
  for (int i = 0; i < 3; i++){
    int idx = t + i * 256;
    float c = w0 * bf2f(r0[idx]) + w1 * bf2f(r1[idx]);
    float xv = hr[idx] + c;
    v[i] = xv; s += xv; sq += xv * xv;
  }
  __shared__ float rs[4], rq[4];
  #pragma unroll
  for (int d = 32; d >= 1; d >>= 1){ s += __shfl_xor(s, d); sq += __shfl_xor(sq, d); }
  int w = t >> 6;
  if ((t & 63) == 0){ rs[w] = s; rq[w] = sq; }
  __syncthreads();
  s = rs[0] + rs[1] + rs[2] + rs[3];
  sq = rq[0] + rq[1] + rq[2] + rq[3];
  float mean = s * (1.f / ND);
  float var = sq * (1.f / ND) - mean * mean;
  float rstd = rsqrtf(var + 1e-5f);
  #pragma unroll
  for (int i = 0; i < 3; i++){
    int idx = t + i * 256;
    float y = (v[i] - mean) * rstd * g[idx] + bb[idx];
    out[(size_t)row * ND + idx] = attn_x[(size_t)row * ND + idx] + y;
  }
}

// ================= host =================
extern "C" void kernel_launch(void* const* d_in, const int* in_sizes, int n_in,
                              void* d_out, int out_size, void* d_ws, size_t ws_size,
                              hipStream_t stream){
  const float* x        = (const float*)d_in[0];
  const float* ln_att_g = (const float*)d_in[2];
  const float* ln_att_b = (const float*)d_in[3];
  const float* wq = (const float*)d_in[4];  const float* bq = (const float*)d_in[5];
  const float* wk = (const float*)d_in[6];  const float* bk = (const float*)d_in[7];
  const float* wv = (const float*)d_in[8];  const float* bv = (const float*)d_in[9];
  const float* wo = (const float*)d_in[10]; const float* bo = (const float*)d_in[11];
  const float* ln_ff_g = (const float*)d_in[12];
  const float* ln_ff_b = (const float*)d_in[13];
  const float* gate_w  = (const float*)d_in[14];
  const float* gate_b  = (const float*)d_in[15];
  const float* w1 = (const float*)d_in[16]; const float* b1 = (const float*)d_in[17];
  const float* w2 = (const float*)d_in[18]; const float* b2 = (const float*)d_in[19];
  const float* moe_g = (const float*)d_in[20];
  const float* moe_b = (const float*)d_in[21];

  uint8_t* p = (uint8_t*)d_ws;
  auto alloc = [&](size_t bytes) -> void* {
    void* r = (void*)p;
    p += (bytes + 255) & ~(size_t)255;
    return r;
  };
  bf16* wqkv_t  = (bf16*)alloc((size_t)2304 * 768 * 2);
  bf16* wo_t    = (bf16*)alloc((size_t)768 * 768 * 2);
  bf16* w1_t    = (bf16*)alloc((size_t)NE * NHID * ND * 2);
  bf16* w2_t    = (bf16*)alloc((size_t)NE * ND * NHID * 2);
  float* bias_qkv = (float*)alloc(2304 * 4);
  bf16* a_bf    = (bf16*)alloc((size_t)NTOK * ND * 2);
  bf16* qkv     = (bf16*)alloc((size_t)NTOK * 2304 * 2);
  bf16* vT      = (bf16*)alloc((size_t)NB * NH * 64 * NS * 2);
  bf16* ctx     = (bf16*)alloc((size_t)NTOK * ND * 2);
  float* attn_x = (float*)alloc((size_t)NTOK * ND * 4);
  float* h_f    = (float*)alloc((size_t)NTOK * ND * 4);
  bf16* h_b     = (bf16*)alloc((size_t)NTOK * ND * 2);
  int*  ridx    = (int*)alloc(NASSIGN * 4);
  float* rwt    = (float*)alloc(NASSIGN * 4);
  int* counts   = (int*)alloc(NE * 4);
  int* poff     = (int*)alloc(NE * 4);
  int* cursor   = (int*)alloc(NE * 4);
  int* chunk_e  = (int*)alloc(MAXCH * 4);
  int* tok_list = (int*)alloc(MAXSLOT * 4);
  int* slot_of  = (int*)alloc(NASSIGN * 4);
  bf16* e1      = (bf16*)alloc((size_t)MAXSLOT * NHID * 2);
  bf16* e2      = (bf16*)alloc((size_t)MAXSLOT * ND * 2);

  hipMemsetAsync(counts, 0, NE * 4, stream);
  hipMemsetAsync(cursor, 0, NE * 4, stream);

  // weight prep
  transpose_convert_kernel<<<dim3(24, 24, 1), 256, 0, stream>>>(wq, wqkv_t, 768, 768);
  transpose_convert_kernel<<<dim3(24, 24, 1), 256, 0, stream>>>(wk, wqkv_t + (size_t)768 * 768, 768, 768);
  transpose_convert_kernel<<<dim3(24, 24, 1), 256, 0, stream>>>(wv, wqkv_t + (size_t)1536 * 768, 768, 768);
  transpose_convert_kernel<<<dim3(24, 24, 1), 256, 0, stream>>>(wo, wo_t, 768, 768);
  transpose_convert_kernel<<<dim3(96, 24, NE), 256, 0, stream>>>(w1, w1_t, 768, 3072);
  transpose_convert_kernel<<<dim3(24, 96, NE), 256, 0, stream>>>(w2, w2_t, 3072, 768);
  concat3_kernel<<<dim3(9), 256, 0, stream>>>(bq, bk, bv, bias_qkv);

  // attention path
  ln_kernel<false, true><<<dim3(NTOK), 256, 0, stream>>>(x, ln_att_g, ln_att_b, nullptr, a_bf);
  gemm_kernel<2, false, false, true, false, false><<<dim3(18, 16), 256, 0, stream>>>(
      a_bf, ND, wqkv_t, bias_qkv, qkv, 2304, nullptr, 2304, ND, nullptr, nullptr);
  vtrans_kernel<<<dim3(32, 2, NB * NH), 256, 0, stream>>>(qkv, vT);
  flash_attn_kernel<<<dim3(16, NH, NB), 256, 0, stream>>>(qkv, vT, ctx);
  gemm_kernel<1, false, false, false, true, false><<<dim3(6, 32), 256, 0, stream>>>(
      ctx, ND, wo_t, bo, attn_x, ND, x, ND, ND, nullptr, nullptr);

  // MoE path
  ln_kernel<true, true><<<dim3(NTOK), 256, 0, stream>>>(attn_x, ln_ff_g, ln_ff_b, h_f, h_b);
  gate_kernel<<<dim3(NTOK / 4), 256, 0, stream>>>(h_f, gate_w, gate_b, ridx, rwt, counts);
  scan_kernel<<<dim3(1), 256, 0, stream>>>(counts, poff, chunk_e, tok_list);
  scatter_kernel<<<dim3(NASSIGN / 256), 256, 0, stream>>>(ridx, poff, cursor, tok_list, slot_of);
  gemm_kernel<2, true, true, true, false, true><<<dim3(24, 36), 256, 0, stream>>>(
      h_b, ND, w1_t, b1, e1, NHID, nullptr, NHID, ND, chunk_e, tok_list);
  gemm_kernel<1, false, false, true, false, true><<<dim3(6, 72), 256, 0, stream>>>(
      e1, NHID, w2_t, b2, e2, ND, nullptr, ND, NHID, chunk_e, nullptr);
  combine_kernel<<<dim3(NTOK), 256, 0, stream>>>(e2, slot_of, rwt, h_f, attn_x, moe_g, moe_b,
                                                 (float*)d_out);
}

// Round 4
// 610.035 us; speedup vs baseline: 1.2691x; 1.1665x over previous
//
#include <hip/hip_runtime.h>
#include <hip/hip_bf16.h>
#include <stdint.h>

using bf16 = __hip_bfloat16;
typedef short s16x8 __attribute__((ext_vector_type(8)));
typedef float f32x4 __attribute__((ext_vector_type(4)));

#define NB 4
#define NS 1024
#define ND 768
#define NH 12
#define NE 8
#define NHID 3072
#define NTOK 4096
#define NASSIGN 8192
#define MAXCH 72               // sum ceil(counts[e]/128) <= 64 + 8
#define MAXSLOT (MAXCH * 128)  // 9216

__device__ __forceinline__ float bf2f(bf16 v){ return __bfloat162float(v); }
__device__ __forceinline__ bf16 f2bf(float v){ return __float2bfloat16(v); }

__device__ __forceinline__ void gload_lds16(const bf16* g, bf16* l){
  __builtin_amdgcn_global_load_lds((const __attribute__((address_space(1))) void*)g,
                                   (__attribute__((address_space(3))) void*)l, 16, 0, 0);
}

// ---------------- transpose + fp32->bf16 convert: src [bz][K][N] -> dst [bz][N][K]
__global__ void transpose_convert_kernel(const float* __restrict__ src, bf16* __restrict__ dst,
                                         int K, int N){
  __shared__ float tile[32][33];
  int bz = blockIdx.z;
  src += (size_t)bz * K * N;
  dst += (size_t)bz * N * K;
  int n0 = blockIdx.x * 32, k0 = blockIdx.y * 32;
  int tx = threadIdx.x & 31, ty = threadIdx.x >> 5; // ty in 0..7
  #pragma unroll
  for (int i = 0; i < 4; i++){
    int k = ty + i * 8;
    tile[k][tx] = src[(size_t)(k0 + k) * N + n0 + tx];
  }
  __syncthreads();
  #pragma unroll
  for (int i = 0; i < 4; i++){
    int n = ty + i * 8;
    dst[(size_t)(n0 + n) * K + k0 + tx] = f2bf(tile[tx][n]);
  }
}

// ---------------- concat 3 bias vectors [768] -> [2304]
__global__ void concat3_kernel(const float* __restrict__ a, const float* __restrict__ b,
                               const float* __restrict__ c, float* __restrict__ out){
  int i = blockIdx.x * 256 + threadIdx.x;
  if (i >= 3 * ND) return;
  float v = (i < ND) ? a[i] : (i < 2 * ND ? b[i - ND] : c[i - 2 * ND]);
  out[i] = v;
}

// ---------------- LayerNorm row kernel (768 per row, 256 threads)
template<bool OF, bool OB>
__global__ void ln_kernel(const float* __restrict__ in, const float* __restrict__ g,
                          const float* __restrict__ bb, float* __restrict__ of,
                          bf16* __restrict__ ob){
  int row = blockIdx.x, t = threadIdx.x;
  const float* x = in + (size_t)row * ND;
  float v[3]; float s = 0.f, sq = 0.f;
  #pragma unroll
  for (int i = 0; i < 3; i++){ v[i] = x[t + i * 256]; s += v[i]; sq += v[i] * v[i]; }
  __shared__ float rs[4], rq[4];
  #pragma unroll
  for (int d = 32; d >= 1; d >>= 1){ s += __shfl_xor(s, d); sq += __shfl_xor(sq, d); }
  int w = t >> 6;
  if ((t & 63) == 0){ rs[w] = s; rq[w] = sq; }
  __syncthreads();
  s = rs[0] + rs[1] + rs[2] + rs[3];
  sq = rq[0] + rq[1] + rq[2] + rq[3];
  float mean = s * (1.f / ND);
  float var = sq * (1.f / ND) - mean * mean;
  float rstd = rsqrtf(var + 1e-5f);
  #pragma unroll
  for (int i = 0; i < 3; i++){
    int idx = t + i * 256;
    float y = (v[i] - mean) * rstd * g[idx] + bb[idx];
    if (OF) of[(size_t)row * ND + idx] = y;
    if (OB) ob[(size_t)row * ND + idx] = f2bf(y);
  }
}

// ---------------- GEMM: C[chunk rows][N] = A @ Bt^T + bias
template<int GROUP, bool GATHER, bool RELU, bool OBF, bool RESID, bool SEG>
__global__ __launch_bounds__(256, 3)
void gemm_kernel(const bf16* __restrict__ A, int ldA,
                 const bf16* __restrict__ BtB,
                 const float* __restrict__ biasB,
                 void* __restrict__ Cv, int ldC,
                 const float* __restrict__ resid,
                 int N, int K,
                 const int* __restrict__ chunk_e, const int* __restrict__ tok){
  __shared__ __align__(16) bf16 sA[2][128 * 32];
  __shared__ __align__(16) bf16 sB[2][128 * 32];

  int t = threadIdx.x;
  int lane = t & 63, wv = t >> 6;
  int c0i = wv * 128 + lane;          // staging chunk id (and c0i+64)
  int r0  = c0i >> 2;                 // tile-local row of chunk0; chunk1 row = r0+16
  int kk  = (c0i & 3) * 8;
  int nt = blockIdx.x;
  int wm = (wv >> 1) * 64, wn = (wv & 1) * 64;
  int l16 = lane & 15, q4 = lane >> 4;
  int aoff[4], boff[4];
  #pragma unroll
  for (int mi = 0; mi < 4; mi++) aoff[mi] = (wm + mi * 16 + l16) * 32 + q4 * 8;
  #pragma unroll
  for (int ni = 0; ni < 4; ni++) boff[ni] = (wn + ni * 16 + l16) * 32 + q4 * 8;

  for (int g = 0; g < GROUP; g++){
    int c = blockIdx.y * GROUP + g;
    int e = 0;
    if (SEG){ e = chunk_e[c]; if (e < 0) break; }
    const bf16* Bt = SEG ? BtB + (size_t)e * N * K : BtB;
    const float* bias = SEG ? biasB + (size_t)e * N : biasB;
    size_t arow0, arow1;
    int m0 = c * 128 + r0, m1 = m0 + 16;
    if (GATHER){ arow0 = (size_t)tok[m0]; arow1 = (size_t)tok[m1]; }
    else       { arow0 = (size_t)m0;      arow1 = (size_t)m1; }
    const bf16* gA0 = A + arow0 * ldA + kk;
    const bf16* gA1 = A + arow1 * ldA + kk;
    const bf16* gB0 = Bt + (size_t)(nt * 128 + r0) * K + kk;
    const bf16* gB1 = Bt + (size_t)(nt * 128 + r0 + 16) * K + kk;

    if (g > 0) __syncthreads();  // protect LDS reuse across chunks

    f32x4 acc[4][4] = {};
    gload_lds16(gA0, &sA[0][(size_t)c0i * 8]);
    gload_lds16(gA1, &sA[0][(size_t)(c0i + 64) * 8]);
    gload_lds16(gB0, &sB[0][(size_t)c0i * 8]);
    gload_lds16(gB1, &sB[0][(size_t)(c0i + 64) * 8]);

    int nk = K >> 5;
    for (int ki = 0; ki < nk; ki++){
      int cur = ki & 1;
      __syncthreads();
      if (ki + 1 < nk){
        int nxt = cur ^ 1, off = (ki + 1) * 32;
        gload_lds16(gA0 + off, &sA[nxt][(size_t)c0i * 8]);
        gload_lds16(gA1 + off, &sA[nxt][(size_t)(c0i + 64) * 8]);
        gload_lds16(gB0 + off, &sB[nxt][(size_t)c0i * 8]);
        gload_lds16(gB1 + off, &sB[nxt][(size_t)(c0i + 64) * 8]);
      }
      s16x8 af[4], bfr[4];
      #pragma unroll
      for (int mi = 0; mi < 4; mi++) af[mi] = *(const s16x8*)(&sA[cur][0] + aoff[mi]);
      #pragma unroll
      for (int ni = 0; ni < 4; ni++) bfr[ni] = *(const s16x8*)(&sB[cur][0] + boff[ni]);
      #pragma unroll
      for (int mi = 0; mi < 4; mi++)
        #pragma unroll
        for (int ni = 0; ni < 4; ni++)
          acc[mi][ni] = __builtin_amdgcn_mfma_f32_16x16x32_bf16(af[mi], bfr[ni], acc[mi][ni], 0, 0, 0);
    }

    #pragma unroll
    for (int mi = 0; mi < 4; mi++){
      #pragma unroll
      for (int ni = 0; ni < 4; ni++){
        int col = nt * 128 + wn + ni * 16 + l16;
        float bv = bias[col];
        #pragma unroll
        for (int r = 0; r < 4; r++){
          size_t crow = (size_t)(c * 128 + wm + mi * 16 + q4 * 4 + r);
          float v = acc[mi][ni][r] + bv;
          if (RELU) v = fmaxf(v, 0.f);
          if (RESID) v += resid[crow * ldC + col];
          if (OBF) ((bf16*)Cv)[crow * ldC + col] = f2bf(v);
          else     ((float*)Cv)[crow * ldC + col] = v;
        }
      }
    }
  }
}

// ---------------- V transpose: qkv v-cols [b,s,h,d] -> vT [b,h,d,s] (bf16)
__global__ void vtrans_kernel(const bf16* __restrict__ qkv, bf16* __restrict__ vT){
  __shared__ bf16 tile[32][33];
  int bh = blockIdx.z; int b = bh / NH, h = bh % NH;
  int s0 = blockIdx.x * 32, d0 = blockIdx.y * 32;
  int tx = threadIdx.x & 31, ty = threadIdx.x >> 5;
  #pragma unroll
  for (int i = 0; i < 4; i++){
    int s = s0 + ty + i * 8;
    tile[ty + i * 8][tx] = qkv[(size_t)(b * NS + s) * 2304 + 1536 + h * 64 + d0 + tx];
  }
  __syncthreads();
  #pragma unroll
  for (int i = 0; i < 4; i++){
    int d = ty + i * 8;
    vT[((size_t)bh * 64 + d0 + d) * NS + s0 + tx] = tile[tx][d];
  }
}

// ---------------- flash attention v2: wave = 16 q-rows, Bc=64 keys/iter
#define SPAD 72   // sP row stride in elems (144 B = 9*16 B: b128-aligned, conflict-free)
__global__ __launch_bounds__(256, 3)
void flash_attn_kernel(const bf16* __restrict__ qkv, const bf16* __restrict__ vT,
                       bf16* __restrict__ ctx){
  __shared__ __align__(16) bf16 sP[4][16 * SPAD];
  int qt = blockIdx.x, h = blockIdx.y, b = blockIdx.z;
  int t = threadIdx.x, lane = t & 63, wv = t >> 6;
  int l16 = lane & 15, q4 = lane >> 4;
  int q0 = qt * 64 + wv * 16;               // this wave's 16 q-rows
  const size_t ldq = 2304;
  const bf16* qbase = qkv + (size_t)(b * NS) * ldq + h * 64;
  const bf16* kbase = qbase + 768;
  const bf16* vtb = vT + (size_t)(b * NH + h) * 64 * NS;
  bf16* sPw = &sP[wv][0];
  const f32x4 fzero = {0.f, 0.f, 0.f, 0.f};

  s16x8 qf[2];
  #pragma unroll
  for (int kh = 0; kh < 2; kh++)
    qf[kh] = *(const s16x8*)(qbase + (size_t)(q0 + l16) * ldq + kh * 32 + q4 * 8);

  f32x4 O[4] = {};
  float ms[4], ls[4];
  #pragma unroll
  for (int r = 0; r < 4; r++){ ms[r] = -1e30f; ls[r] = 0.f; }

  int kend = q0 + 16;  // need keys <= q0+15
  for (int key0 = 0; key0 < kend; key0 += 64){
    s16x8 kf[4][2];
    #pragma unroll
    for (int ni = 0; ni < 4; ni++)
      #pragma unroll
      for (int kh = 0; kh < 2; kh++)
        kf[ni][kh] = *(const s16x8*)(kbase + (size_t)(key0 + ni * 16 + l16) * ldq + kh * 32 + q4 * 8);
    f32x4 Sf[4];
    #pragma unroll
    for (int ni = 0; ni < 4; ni++){
      Sf[ni] = __builtin_amdgcn_mfma_f32_16x16x32_bf16(qf[0], kf[ni][0], fzero, 0, 0, 0);
      Sf[ni] = __builtin_amdgcn_mfma_f32_16x16x32_bf16(qf[1], kf[ni][1], Sf[ni], 0, 0, 0);
    }
    s16x8 vf[4][2];
    #pragma unroll
    for (int dt = 0; dt < 4; dt++)
      #pragma unroll
      for (int kh = 0; kh < 2; kh++)
        vf[dt][kh] = *(const s16x8*)(vtb + (size_t)(dt * 16 + l16) * NS + key0 + kh * 32 + q4 * 8);

    bool need_mask = (key0 + 63 >= q0);  // wave-uniform
    #pragma unroll
    for (int r = 0; r < 4; r++){
      int qrow = q0 + q4 * 4 + r;
      float sv[4];
      #pragma unroll
      for (int ni = 0; ni < 4; ni++){
        sv[ni] = Sf[ni][r] * 0.125f;
        if (need_mask && (key0 + ni * 16 + l16 > qrow)) sv[ni] = -1e30f;
      }
      float mx = fmaxf(fmaxf(sv[0], sv[1]), fmaxf(sv[2], sv[3]));
      #pragma unroll
      for (int d = 8; d >= 1; d >>= 1) mx = fmaxf(mx, __shfl_xor(mx, d));
      float mnew = fmaxf(ms[r], mx);
      float alpha = __expf(ms[r] - mnew);
      float p[4], psum = 0.f;
      #pragma unroll
      for (int ni = 0; ni < 4; ni++){ p[ni] = __expf(sv[ni] - mnew); psum += p[ni]; }
      #pragma unroll
      for (int d = 8; d >= 1; d >>= 1) psum += __shfl_xor(psum, d);
      ls[r] = ls[r] * alpha + psum;
      ms[r] = mnew;
      #pragma unroll
      for (int dt = 0; dt < 4; dt++) O[dt][r] *= alpha;
      int prow = q4 * 4 + r;
      #pragma unroll
      for (int ni = 0; ni < 4; ni++)
        sPw[prow * SPAD + ni * 16 + l16] = f2bf(p[ni]);
    }
    s16x8 pf[2];
    #pragma unroll
    for (int kh = 0; kh < 2; kh++)
      pf[kh] = *(const s16x8*)(sPw + l16 * SPAD + kh * 32 + q4 * 8);
    #pragma unroll
    for (int dt = 0; dt < 4; dt++){
      O[dt] = __builtin_amdgcn_mfma_f32_16x16x32_bf16(pf[0], vf[dt][0], O[dt], 0, 0, 0);
      O[dt] = __builtin_amdgcn_mfma_f32_16x16x32_bf16(pf[1], vf[dt][1], O[dt], 0, 0, 0);
    }
  }

  #pragma unroll
  for (int r = 0; r < 4; r++){
    float inv = 1.f / ls[r];
    int qrow = q0 + q4 * 4 + r;
    #pragma unroll
    for (int dt = 0; dt < 4; dt++)
      ctx[(size_t)(b * NS + qrow) * ND + h * 64 + dt * 16 + l16] = f2bf(O[dt][r] * inv);
  }
}

// ---------------- gate v2: 128 blocks x 32 tokens; LDS count aggregation
__global__ __launch_bounds__(256)
void gate_kernel(const float* __restrict__ h, const float* __restrict__ gw,
                 const float* __restrict__ gb, int* __restrict__ ridx,
                 float* __restrict__ rw, int* __restrict__ counts){
  __shared__ float sgw[NE * ND];   // transposed: sgw[e*ND+i] -> stride-1 reads
  __shared__ int scnt[NE];
  int t = threadIdx.x;
  if (t < NE) scnt[t] = 0;
  for (int idx = t; idx < ND * NE; idx += 256){
    int i = idx >> 3, e = idx & 7;
    sgw[e * ND + i] = gw[idx];
  }
  __syncthreads();
  int lane = t & 63, wv = t >> 6;
  for (int it = 0; it < 8; it++){
    int tok = blockIdx.x * 32 + it * 4 + wv;
    const float* hr = h + (size_t)tok * ND;
    float acc[NE] = {};
    #pragma unroll
    for (int ii = 0; ii < 12; ii++){
      int i = lane + ii * 64;
      float hv = hr[i];
      #pragma unroll
      for (int e = 0; e < NE; e++) acc[e] += hv * sgw[e * ND + i];
    }
    #pragma unroll
    for (int e = 0; e < NE; e++)
      #pragma unroll
      for (int d = 32; d >= 1; d >>= 1) acc[e] += __shfl_xor(acc[e], d);
    if (lane == 0){
      float v0 = -1e30f, v1 = -1e30f; int i0 = 0, i1 = 0;
      #pragma unroll
      for (int e = 0; e < NE; e++){
        float v = acc[e] + gb[e];
        if (v > v0){ v1 = v0; i1 = i0; v0 = v; i0 = e; }
        else if (v > v1){ v1 = v; i1 = e; }
      }
      float w0 = 1.f / (1.f + __expf(v1 - v0));
      ridx[tok * 2] = i0; ridx[tok * 2 + 1] = i1;
      rw[tok * 2] = w0;  rw[tok * 2 + 1] = 1.f - w0;
      atomicAdd(&scnt[i0], 1);
      atomicAdd(&scnt[i1], 1);
    }
  }
  __syncthreads();
  if (t < NE) atomicAdd(&counts[t], scnt[t]);
}

// scan: padded (128-aligned) expert offsets + chunk->expert map + tok_list prefill
__global__ void scan_kernel(const int* __restrict__ counts, int* __restrict__ poff,
                            int* __restrict__ chunk_e, int* __restrict__ tok_list){
  int t = threadIdx.x;
  for (int i = t; i < MAXSLOT; i += 256) tok_list[i] = 0;
  if (t == 0){
    int s = 0, c = 0;
    for (int e = 0; e < NE; e++){
      poff[e] = s;
      int nch = (counts[e] + 127) >> 7;
      for (int i = 0; i < nch; i++) chunk_e[c++] = e;
      s += nch << 7;
    }
    for (; c < MAXCH; c++) chunk_e[c] = -1;
  }
}

// scatter v2: wave-aggregated atomics (1 atomic per expert per wave)
__global__ void scatter_kernel(const int* __restrict__ ridx, const int* __restrict__ poff,
                               int* __restrict__ cursor, int* __restrict__ tok_list,
                               int* __restrict__ slot_of){
  int tk = blockIdx.x * 256 + threadIdx.x;
  int lane = threadIdx.x & 63;
  int e = ridx[tk];
  unsigned long long lmask = (lane == 63) ? ~0ull : ((1ull << (lane + 1)) - 1);
  lmask >>= 1; lmask <<= 1; lmask = (1ull << lane) - 1;  // bits below lane
  int slot = 0;
  #pragma unroll
  for (int ee = 0; ee < NE; ee++){
    unsigned long long mask = __ballot(e == ee);
    if (mask == 0ull) continue;
    int leader = __ffsll((unsigned long long)mask) - 1;
    int base = 0;
    if (lane == leader) base = atomicAdd(&cursor[ee], __popcll(mask));
    base = __shfl(base, leader);
    if (e == ee) slot = poff[ee] + base + __popcll(mask & lmask);
  }
  tok_list[slot] = tk >> 1;
  slot_of[tk] = slot;
}

// ---------------- combine: core = w0*e2[s0]+w1*e2[s1]; out = attn_x + LN(h+core)
__global__ void combine_kernel(const bf16* __restrict__ e2, const int* __restrict__ slot_of,
                               const float* __restrict__ rw, const float* __restrict__ hf,
                               const float* __restrict__ attn_x, const float* __restrict__ g,
                               const float* __restrict__ bb, float* __restrict__ out){
  int row = blockIdx.x, t = threadIdx.x;
  int sl0 = slot_of[row * 2], sl1 = slot_of[row * 2 + 1];
  float w0 = rw[row * 2], w1 = rw[row * 2 + 1];
  const bf16* r0 = e2 + (size_t)sl0 * ND;
  const bf16* r1 = e2 + (size_t)sl1 * ND;
  const float* hr = hf + (size_t)row * ND;
  float v[3]; float s = 0.f, sq = 0.f;
  #pragma unroll
  for (int i = 0; i < 3; i++){
    int idx = t + i * 256;
    float c = w0 * bf2f(r0[idx]) + w1 * bf2f(r1[idx]);
    float xv = hr[idx] + c;
    v[i] = xv; s += xv; sq += xv * xv;
  }
  __shared__ float rs[4], rq[4];
  #pragma unroll
  for (int d = 32; d >= 1; d >>= 1){ s += __shfl_xor(s, d); sq += __shfl_xor(sq, d); }
  int w = t >> 6;
  if ((t & 63) == 0){ rs[w] = s; rq[w] = sq; }
  __syncthreads();
  s = rs[0] + rs[1] + rs[2] + rs[3];
  sq = rq[0] + rq[1] + rq[2] + rq[3];
  float mean = s * (1.f / ND);
  float var = sq * (1.f / ND) - mean * mean;
  float rstd = rsqrtf(var + 1e-5f);
  #pragma unroll
  for (int i = 0; i < 3; i++){
    int idx = t + i * 256;
    float y = (v[i] - mean) * rstd * g[idx] + bb[idx];
    out[(size_t)row * ND + idx] = attn_x[(size_t)row * ND + idx] + y;
  }
}

// ================= host =================
extern "C" void kernel_launch(void* const* d_in, const int* in_sizes, int n_in,
                              void* d_out, int out_size, void* d_ws, size_t ws_size,
                              hipStream_t stream){
  const float* x        = (const float*)d_in[0];
  const float* ln_att_g = (const float*)d_in[2];
  const float* ln_att_b = (const float*)d_in[3];
  const float* wq = (const float*)d_in[4];  const float* bq = (const float*)d_in[5];
  const float* wk = (const float*)d_in[6];  const float* bk = (const float*)d_in[7];
  const float* wv = (const float*)d_in[8];  const float* bv = (const float*)d_in[9];
  const float* wo = (const float*)d_in[10]; const float* bo = (const float*)d_in[11];
  const float* ln_ff_g = (const float*)d_in[12];
  const float* ln_ff_b = (const float*)d_in[13];
  const float* gate_w  = (const float*)d_in[14];
  const float* gate_b  = (const float*)d_in[15];
  const float* w1 = (const float*)d_in[16]; const float* b1 = (const float*)d_in[17];
  const float* w2 = (const float*)d_in[18]; const float* b2 = (const float*)d_in[19];
  const float* moe_g = (const float*)d_in[20];
  const float* moe_b = (const float*)d_in[21];

  uint8_t* p = (uint8_t*)d_ws;
  auto alloc = [&](size_t bytes) -> void* {
    void* r = (void*)p;
    p += (bytes + 255) & ~(size_t)255;
    return r;
  };
  bf16* wqkv_t  = (bf16*)alloc((size_t)2304 * 768 * 2);
  bf16* wo_t    = (bf16*)alloc((size_t)768 * 768 * 2);
  bf16* w1_t    = (bf16*)alloc((size_t)NE * NHID * ND * 2);
  bf16* w2_t    = (bf16*)alloc((size_t)NE * ND * NHID * 2);
  float* bias_qkv = (float*)alloc(2304 * 4);
  bf16* a_bf    = (bf16*)alloc((size_t)NTOK * ND * 2);
  bf16* qkv     = (bf16*)alloc((size_t)NTOK * 2304 * 2);
  bf16* vT      = (bf16*)alloc((size_t)NB * NH * 64 * NS * 2);
  bf16* ctx     = (bf16*)alloc((size_t)NTOK * ND * 2);
  float* attn_x = (float*)alloc((size_t)NTOK * ND * 4);
  float* h_f    = (float*)alloc((size_t)NTOK * ND * 4);
  bf16* h_b     = (bf16*)alloc((size_t)NTOK * ND * 2);
  int*  ridx    = (int*)alloc(NASSIGN * 4);
  float* rwt    = (float*)alloc(NASSIGN * 4);
  int* counts   = (int*)alloc(NE * 4);
  int* poff     = (int*)alloc(NE * 4);
  int* cursor   = (int*)alloc(NE * 4);
  int* chunk_e  = (int*)alloc(MAXCH * 4);
  int* tok_list = (int*)alloc(MAXSLOT * 4);
  int* slot_of  = (int*)alloc(NASSIGN * 4);
  bf16* e1      = (bf16*)alloc((size_t)MAXSLOT * NHID * 2);
  bf16* e2      = (bf16*)alloc((size_t)MAXSLOT * ND * 2);

  hipMemsetAsync(counts, 0, NE * 4, stream);
  hipMemsetAsync(cursor, 0, NE * 4, stream);

  // weight prep
  transpose_convert_kernel<<<dim3(24, 24, 1), 256, 0, stream>>>(wq, wqkv_t, 768, 768);
  transpose_convert_kernel<<<dim3(24, 24, 1), 256, 0, stream>>>(wk, wqkv_t + (size_t)768 * 768, 768, 768);
  transpose_convert_kernel<<<dim3(24, 24, 1), 256, 0, stream>>>(wv, wqkv_t + (size_t)1536 * 768, 768, 768);
  transpose_convert_kernel<<<dim3(24, 24, 1), 256, 0, stream>>>(wo, wo_t, 768, 768);
  transpose_convert_kernel<<<dim3(96, 24, NE), 256, 0, stream>>>(w1, w1_t, 768, 3072);
  transpose_convert_kernel<<<dim3(24, 96, NE), 256, 0, stream>>>(w2, w2_t, 3072, 768);
  concat3_kernel<<<dim3(9), 256, 0, stream>>>(bq, bk, bv, bias_qkv);

  // attention path
  ln_kernel<false, true><<<dim3(NTOK), 256, 0, stream>>>(x, ln_att_g, ln_att_b, nullptr, a_bf);
  gemm_kernel<2, false, false, true, false, false><<<dim3(18, 16), 256, 0, stream>>>(
      a_bf, ND, wqkv_t, bias_qkv, qkv, 2304, nullptr, 2304, ND, nullptr, nullptr);
  vtrans_kernel<<<dim3(32, 2, NB * NH), 256, 0, stream>>>(qkv, vT);
  flash_attn_kernel<<<dim3(16, NH, NB), 256, 0, stream>>>(qkv, vT, ctx);
  gemm_kernel<1, false, false, false, true, false><<<dim3(6, 32), 256, 0, stream>>>(
      ctx, ND, wo_t, bo, attn_x, ND, x, ND, ND, nullptr, nullptr);

  // MoE path
  ln_kernel<true, true><<<dim3(NTOK), 256, 0, stream>>>(attn_x, ln_ff_g, ln_ff_b, h_f, h_b);
  gate_kernel<<<dim3(NTOK / 32), 256, 0, stream>>>(h_f, gate_w, gate_b, ridx, rwt, counts);
  scan_kernel<<<dim3(1), 256, 0, stream>>>(counts, poff, chunk_e, tok_list);
  scatter_kernel<<<dim3(NASSIGN / 256), 256, 0, stream>>>(ridx, poff, cursor, tok_list, slot_of);
  gemm_kernel<2, true, true, true, false, true><<<dim3(24, 36), 256, 0, stream>>>(
      h_b, ND, w1_t, b1, e1, NHID, nullptr, NHID, ND, chunk_e, tok_list);
  gemm_kernel<1, false, false, true, false, true><<<dim3(6, 72), 256, 0, stream>>>(
      e1, NHID, w2_t, b2, e2, ND, nullptr, ND, NHID, chunk_e, nullptr);
  combine_kernel<<<dim3(NTOK), 256, 0, stream>>>(e2, slot_of, rwt, h_f, attn_x, moe_g, moe_b,
                                                 (float*)d_out);
}

// Round 5
// 553.924 us; speedup vs baseline: 1.3977x; 1.1013x over previous
//
#include <hip/hip_runtime.h>
#include <hip/hip_bf16.h>
#include <stdint.h>

using bf16 = __hip_bfloat16;
typedef short s16x8 __attribute__((ext_vector_type(8)));
typedef float f32x4 __attribute__((ext_vector_type(4)));

#define NB 4
#define NS 1024
#define ND 768
#define NH 12
#define NE 8
#define NHID 3072
#define NTOK 4096
#define NASSIGN 8192
#define MAXCH 72               // sum ceil(counts[e]/128) <= 64 + 8
#define MAXSLOT (MAXCH * 128)  // 9216

__device__ __forceinline__ float bf2f(bf16 v){ return __bfloat162float(v); }
__device__ __forceinline__ bf16 f2bf(float v){ return __float2bfloat16(v); }

__device__ __forceinline__ void gload_lds16(const bf16* g, bf16* l){
  __builtin_amdgcn_global_load_lds((const __attribute__((address_space(1))) void*)g,
                                   (__attribute__((address_space(3))) void*)l, 16, 0, 0);
}

// ---------------- transpose + fp32->bf16 convert: src [bz][K][N] -> dst [bz][N][K]
__global__ void transpose_convert_kernel(const float* __restrict__ src, bf16* __restrict__ dst,
                                         int K, int N){
  __shared__ float tile[32][33];
  int bz = blockIdx.z;
  src += (size_t)bz * K * N;
  dst += (size_t)bz * N * K;
  int n0 = blockIdx.x * 32, k0 = blockIdx.y * 32;
  int tx = threadIdx.x & 31, ty = threadIdx.x >> 5; // ty in 0..7
  #pragma unroll
  for (int i = 0; i < 4; i++){
    int k = ty + i * 8;
    tile[k][tx] = src[(size_t)(k0 + k) * N + n0 + tx];
  }
  __syncthreads();
  #pragma unroll
  for (int i = 0; i < 4; i++){
    int n = ty + i * 8;
    dst[(size_t)(n0 + n) * K + k0 + tx] = f2bf(tile[tx][n]);
  }
}

// ---------------- concat 3 bias vectors [768] -> [2304]
__global__ void concat3_kernel(const float* __restrict__ a, const float* __restrict__ b,
                               const float* __restrict__ c, float* __restrict__ out){
  int i = blockIdx.x * 256 + threadIdx.x;
  if (i >= 3 * ND) return;
  float v = (i < ND) ? a[i] : (i < 2 * ND ? b[i - ND] : c[i - 2 * ND]);
  out[i] = v;
}

// ---------------- LayerNorm row kernel (768 per row, 256 threads)
template<bool OF, bool OB>
__global__ void ln_kernel(const float* __restrict__ in, const float* __restrict__ g,
                          const float* __restrict__ bb, float* __restrict__ of,
                          bf16* __restrict__ ob){
  int row = blockIdx.x, t = threadIdx.x;
  const float* x = in + (size_t)row * ND;
  float v[3]; float s = 0.f, sq = 0.f;
  #pragma unroll
  for (int i = 0; i < 3; i++){ v[i] = x[t + i * 256]; s += v[i]; sq += v[i] * v[i]; }
  __shared__ float rs[4], rq[4];
  #pragma unroll
  for (int d = 32; d >= 1; d >>= 1){ s += __shfl_xor(s, d); sq += __shfl_xor(sq, d); }
  int w = t >> 6;
  if ((t & 63) == 0){ rs[w] = s; rq[w] = sq; }
  __syncthreads();
  s = rs[0] + rs[1] + rs[2] + rs[3];
  sq = rq[0] + rq[1] + rq[2] + rq[3];
  float mean = s * (1.f / ND);
  float var = sq * (1.f / ND) - mean * mean;
  float rstd = rsqrtf(var + 1e-5f);
  #pragma unroll
  for (int i = 0; i < 3; i++){
    int idx = t + i * 256;
    float y = (v[i] - mean) * rstd * g[idx] + bb[idx];
    if (OF) of[(size_t)row * ND + idx] = y;
    if (OB) ob[(size_t)row * ND + idx] = f2bf(y);
  }
}

// ---------------- GEMM: C[chunk rows][N] = A @ Bt^T + bias
template<int GROUP, bool GATHER, bool RELU, bool OBF, bool RESID, bool SEG>
__global__ __launch_bounds__(256, 3)
void gemm_kernel(const bf16* __restrict__ A, int ldA,
                 const bf16* __restrict__ BtB,
                 const float* __restrict__ biasB,
                 void* __restrict__ Cv, int ldC,
                 const float* __restrict__ resid,
                 int N, int K,
                 const int* __restrict__ chunk_e, const int* __restrict__ tok){
  __shared__ __align__(16) bf16 sA[2][128 * 32];
  __shared__ __align__(16) bf16 sB[2][128 * 32];

  int t = threadIdx.x;
  int lane = t & 63, wv = t >> 6;
  int c0i = wv * 128 + lane;          // staging chunk id (and c0i+64)
  int r0  = c0i >> 2;                 // tile-local row of chunk0; chunk1 row = r0+16
  int kk  = (c0i & 3) * 8;
  int nt = blockIdx.x;
  int wm = (wv >> 1) * 64, wn = (wv & 1) * 64;
  int l16 = lane & 15, q4 = lane >> 4;
  int aoff[4], boff[4];
  #pragma unroll
  for (int mi = 0; mi < 4; mi++) aoff[mi] = (wm + mi * 16 + l16) * 32 + q4 * 8;
  #pragma unroll
  for (int ni = 0; ni < 4; ni++) boff[ni] = (wn + ni * 16 + l16) * 32 + q4 * 8;

  for (int g = 0; g < GROUP; g++){
    int c = blockIdx.y * GROUP + g;
    int e = 0;
    if (SEG){ e = chunk_e[c]; if (e < 0) break; }
    const bf16* Bt = SEG ? BtB + (size_t)e * N * K : BtB;
    const float* bias = SEG ? biasB + (size_t)e * N : biasB;
    size_t arow0, arow1;
    int m0 = c * 128 + r0, m1 = m0 + 16;
    if (GATHER){ arow0 = (size_t)tok[m0]; arow1 = (size_t)tok[m1]; }
    else       { arow0 = (size_t)m0;      arow1 = (size_t)m1; }
    const bf16* gA0 = A + arow0 * ldA + kk;
    const bf16* gA1 = A + arow1 * ldA + kk;
    const bf16* gB0 = Bt + (size_t)(nt * 128 + r0) * K + kk;
    const bf16* gB1 = Bt + (size_t)(nt * 128 + r0 + 16) * K + kk;

    if (g > 0) __syncthreads();  // protect LDS reuse across chunks

    f32x4 acc[4][4] = {};
    gload_lds16(gA0, &sA[0][(size_t)c0i * 8]);
    gload_lds16(gA1, &sA[0][(size_t)(c0i + 64) * 8]);
    gload_lds16(gB0, &sB[0][(size_t)c0i * 8]);
    gload_lds16(gB1, &sB[0][(size_t)(c0i + 64) * 8]);

    int nk = K >> 5;
    for (int ki = 0; ki < nk; ki++){
      int cur = ki & 1;
      __syncthreads();
      if (ki + 1 < nk){
        int nxt = cur ^ 1, off = (ki + 1) * 32;
        gload_lds16(gA0 + off, &sA[nxt][(size_t)c0i * 8]);
        gload_lds16(gA1 + off, &sA[nxt][(size_t)(c0i + 64) * 8]);
        gload_lds16(gB0 + off, &sB[nxt][(size_t)c0i * 8]);
        gload_lds16(gB1 + off, &sB[nxt][(size_t)(c0i + 64) * 8]);
      }
      s16x8 af[4], bfr[4];
      #pragma unroll
      for (int mi = 0; mi < 4; mi++) af[mi] = *(const s16x8*)(&sA[cur][0] + aoff[mi]);
      #pragma unroll
      for (int ni = 0; ni < 4; ni++) bfr[ni] = *(const s16x8*)(&sB[cur][0] + boff[ni]);
      #pragma unroll
      for (int mi = 0; mi < 4; mi++)
        #pragma unroll
        for (int ni = 0; ni < 4; ni++)
          acc[mi][ni] = __builtin_amdgcn_mfma_f32_16x16x32_bf16(af[mi], bfr[ni], acc[mi][ni], 0, 0, 0);
    }

    #pragma unroll
    for (int mi = 0; mi < 4; mi++){
      #pragma unroll
      for (int ni = 0; ni < 4; ni++){
        int col = nt * 128 + wn + ni * 16 + l16;
        float bv = bias[col];
        #pragma unroll
        for (int r = 0; r < 4; r++){
          size_t crow = (size_t)(c * 128 + wm + mi * 16 + q4 * 4 + r);
          float v = acc[mi][ni][r] + bv;
          if (RELU) v = fmaxf(v, 0.f);
          if (RESID) v += resid[crow * ldC + col];
          if (OBF) ((bf16*)Cv)[crow * ldC + col] = f2bf(v);
          else     ((float*)Cv)[crow * ldC + col] = v;
        }
      }
    }
  }
}

// ---------------- V transpose: qkv v-cols [b,s,h,d] -> vT [b,h,d,s] (bf16)
__global__ void vtrans_kernel(const bf16* __restrict__ qkv, bf16* __restrict__ vT){
  __shared__ bf16 tile[32][33];
  int bh = blockIdx.z; int b = bh / NH, h = bh % NH;
  int s0 = blockIdx.x * 32, d0 = blockIdx.y * 32;
  int tx = threadIdx.x & 31, ty = threadIdx.x >> 5;
  #pragma unroll
  for (int i = 0; i < 4; i++){
    int s = s0 + ty + i * 8;
    tile[ty + i * 8][tx] = qkv[(size_t)(b * NS + s) * 2304 + 1536 + h * 64 + d0 + tx];
  }
  __syncthreads();
  #pragma unroll
  for (int i = 0; i < 4; i++){
    int d = ty + i * 8;
    vT[((size_t)bh * 64 + d0 + d) * NS + s0 + tx] = tile[tx][d];
  }
}

// ---------------- flash attention v3: block-cooperative LDS K/V staging, dbuf
// block = 4 waves x 16 q-rows = 64 q; grid 768 1-D; id = qtr*48 + bh so all
// q-tiles of one (b,h) hit the same XCD (round-robin % 8), long blocks first.
// K/V tiles staged 64x64 bf16 with XOR col swizzle (phys c16 = logical ^ row&7)
// because global_load_lds dest is wave-uniform base + lane*16 (no padding).
#define SPAD 72
__global__ __launch_bounds__(256, 3)
void flash_attn_kernel(const bf16* __restrict__ qkv, const bf16* __restrict__ vT,
                       bf16* __restrict__ ctx){
  __shared__ __align__(16) bf16 sK[2][64 * 64];
  __shared__ __align__(16) bf16 sV[2][64 * 64];
  __shared__ __align__(16) bf16 sP[4][16 * SPAD];
  int id = blockIdx.x;
  int bh = id % 48;
  int qt = 15 - (id / 48);
  int b = bh / NH, h = bh % NH;
  int t = threadIdx.x, lane = t & 63, wv = t >> 6;
  int l16 = lane & 15, q4 = lane >> 4;
  int q0 = qt * 64 + wv * 16;
  const size_t ldq = 2304;
  const bf16* qbase = qkv + (size_t)(b * NS) * ldq + h * 64;
  const bf16* kbase = qbase + 768;
  const bf16* vtb = vT + (size_t)bh * 64 * NS;
  bf16* sPw = &sP[wv][0];
  const f32x4 fzero = {0.f, 0.f, 0.f, 0.f};

  s16x8 qf[2];
  #pragma unroll
  for (int kh = 0; kh < 2; kh++)
    qf[kh] = *(const s16x8*)(qbase + (size_t)(q0 + l16) * ldq + kh * 32 + q4 * 8);

  f32x4 O[4] = {};
  float ms[4], ls[4];
  #pragma unroll
  for (int r = 0; r < 4; r++){ ms[r] = -1e30f; ls[r] = 0.f; }

  int sub = lane >> 3, rawc = lane & 7;
  auto stage = [&](int buf, int key0){
    #pragma unroll
    for (int i = 0; i < 2; i++){
      int rk = wv * 8 + sub + i * 32;          // key row (K) / dh row (V)
      int cs = (rawc ^ (rk & 7)) * 8;          // swizzled source col (elems)
      gload_lds16(kbase + (size_t)(key0 + rk) * ldq + cs, &sK[buf][wv * 512 + i * 2048]);
      gload_lds16(vtb + (size_t)rk * NS + key0 + cs,      &sV[buf][wv * 512 + i * 2048]);
    }
  };

  int ntiles = qt + 1;
  stage(0, 0);
  for (int ti = 0; ti < ntiles; ti++){
    int cur = ti & 1, key0 = ti * 64;
    __syncthreads();                       // drains own staging loads + barrier
    if (ti + 1 < ntiles) stage(cur ^ 1, (ti + 1) * 64);
    if (key0 <= q0 + 15){
      const bf16* sKc = &sK[cur][0];
      const bf16* sVc = &sV[cur][0];
      s16x8 kf[4][2], vf[4][2];
      #pragma unroll
      for (int ni = 0; ni < 4; ni++){
        int krow = ni * 16 + l16;
        #pragma unroll
        for (int kh = 0; kh < 2; kh++)
          kf[ni][kh] = *(const s16x8*)(sKc + krow * 64 + (((kh * 4 + q4) ^ (krow & 7)) * 8));
      }
      #pragma unroll
      for (int dt = 0; dt < 4; dt++){
        int vrow = dt * 16 + l16;
        #pragma unroll
        for (int kh = 0; kh < 2; kh++)
          vf[dt][kh] = *(const s16x8*)(sVc + vrow * 64 + (((kh * 4 + q4) ^ (vrow & 7)) * 8));
      }
      f32x4 Sf[4];
      #pragma unroll
      for (int ni = 0; ni < 4; ni++){
        Sf[ni] = __builtin_amdgcn_mfma_f32_16x16x32_bf16(qf[0], kf[ni][0], fzero, 0, 0, 0);
        Sf[ni] = __builtin_amdgcn_mfma_f32_16x16x32_bf16(qf[1], kf[ni][1], Sf[ni], 0, 0, 0);
      }
      bool need_mask = (key0 + 63 >= q0);  // wave-uniform
      #pragma unroll
      for (int r = 0; r < 4; r++){
        int qrow = q0 + q4 * 4 + r;
        float sv[4];
        #pragma unroll
        for (int ni = 0; ni < 4; ni++){
          sv[ni] = Sf[ni][r] * 0.125f;
          if (need_mask && (key0 + ni * 16 + l16 > qrow)) sv[ni] = -1e30f;
        }
        float mx = fmaxf(fmaxf(sv[0], sv[1]), fmaxf(sv[2], sv[3]));
        #pragma unroll
        for (int d = 8; d >= 1; d >>= 1) mx = fmaxf(mx, __shfl_xor(mx, d));
        float mnew = fmaxf(ms[r], mx);
        float alpha = __expf(ms[r] - mnew);
        float p[4], psum = 0.f;
        #pragma unroll
        for (int ni = 0; ni < 4; ni++){ p[ni] = __expf(sv[ni] - mnew); psum += p[ni]; }
        #pragma unroll
        for (int d = 8; d >= 1; d >>= 1) psum += __shfl_xor(psum, d);
        ls[r] = ls[r] * alpha + psum;
        ms[r] = mnew;
        #pragma unroll
        for (int dt = 0; dt < 4; dt++) O[dt][r] *= alpha;
        int prow = q4 * 4 + r;
        #pragma unroll
        for (int ni = 0; ni < 4; ni++)
          sPw[prow * SPAD + ni * 16 + l16] = f2bf(p[ni]);
      }
      s16x8 pf[2];
      #pragma unroll
      for (int kh = 0; kh < 2; kh++)
        pf[kh] = *(const s16x8*)(sPw + l16 * SPAD + kh * 32 + q4 * 8);
      #pragma unroll
      for (int dt = 0; dt < 4; dt++){
        O[dt] = __builtin_amdgcn_mfma_f32_16x16x32_bf16(pf[0], vf[dt][0], O[dt], 0, 0, 0);
        O[dt] = __builtin_amdgcn_mfma_f32_16x16x32_bf16(pf[1], vf[dt][1], O[dt], 0, 0, 0);
      }
    }
  }

  #pragma unroll
  for (int r = 0; r < 4; r++){
    float inv = 1.f / ls[r];
    int qrow = q0 + q4 * 4 + r;
    #pragma unroll
    for (int dt = 0; dt < 4; dt++)
      ctx[(size_t)(b * NS + qrow) * ND + h * 64 + dt * 16 + l16] = f2bf(O[dt][r] * inv);
  }
}

// ---------------- gate v2: 128 blocks x 32 tokens; LDS count aggregation
__global__ __launch_bounds__(256)
void gate_kernel(const float* __restrict__ h, const float* __restrict__ gw,
                 const float* __restrict__ gb, int* __restrict__ ridx,
                 float* __restrict__ rw, int* __restrict__ counts){
  __shared__ float sgw[NE * ND];   // transposed: sgw[e*ND+i] -> stride-1 reads
  __shared__ int scnt[NE];
  int t = threadIdx.x;
  if (t < NE) scnt[t] = 0;
  for (int idx = t; idx < ND * NE; idx += 256){
    int i = idx >> 3, e = idx & 7;
    sgw[e * ND + i] = gw[idx];
  }
  __syncthreads();
  int lane = t & 63, wv = t >> 6;
  for (int it = 0; it < 8; it++){
    int tok = blockIdx.x * 32 + it * 4 + wv;
    const float* hr = h + (size_t)tok * ND;
    float acc[NE] = {};
    #pragma unroll
    for (int ii = 0; ii < 12; ii++){
      int i = lane + ii * 64;
      float hv = hr[i];
      #pragma unroll
      for (int e = 0; e < NE; e++) acc[e] += hv * sgw[e * ND + i];
    }
    #pragma unroll
    for (int e = 0; e < NE; e++)
      #pragma unroll
      for (int d = 32; d >= 1; d >>= 1) acc[e] += __shfl_xor(acc[e], d);
    if (lane == 0){
      float v0 = -1e30f, v1 = -1e30f; int i0 = 0, i1 = 0;
      #pragma unroll
      for (int e = 0; e < NE; e++){
        float v = acc[e] + gb[e];
        if (v > v0){ v1 = v0; i1 = i0; v0 = v; i0 = e; }
        else if (v > v1){ v1 = v; i1 = e; }
      }
      float w0 = 1.f / (1.f + __expf(v1 - v0));
      ridx[tok * 2] = i0; ridx[tok * 2 + 1] = i1;
      rw[tok * 2] = w0;  rw[tok * 2 + 1] = 1.f - w0;
      atomicAdd(&scnt[i0], 1);
      atomicAdd(&scnt[i1], 1);
    }
  }
  __syncthreads();
  if (t < NE) atomicAdd(&counts[t], scnt[t]);
}

// scan: padded (128-aligned) expert offsets + chunk->expert map + tok_list prefill
__global__ void scan_kernel(const int* __restrict__ counts, int* __restrict__ poff,
                            int* __restrict__ chunk_e, int* __restrict__ tok_list){
  int t = threadIdx.x;
  for (int i = t; i < MAXSLOT; i += 256) tok_list[i] = 0;
  if (t == 0){
    int s = 0, c = 0;
    for (int e = 0; e < NE; e++){
      poff[e] = s;
      int nch = (counts[e] + 127) >> 7;
      for (int i = 0; i < nch; i++) chunk_e[c++] = e;
      s += nch << 7;
    }
    for (; c < MAXCH; c++) chunk_e[c] = -1;
  }
}

// scatter v2: wave-aggregated atomics (1 atomic per expert per wave)
__global__ void scatter_kernel(const int* __restrict__ ridx, const int* __restrict__ poff,
                               int* __restrict__ cursor, int* __restrict__ tok_list,
                               int* __restrict__ slot_of){
  int tk = blockIdx.x * 256 + threadIdx.x;
  int lane = threadIdx.x & 63;
  int e = ridx[tk];
  unsigned long long lmask = (1ull << lane) - 1;  // bits below lane
  int slot = 0;
  #pragma unroll
  for (int ee = 0; ee < NE; ee++){
    unsigned long long mask = __ballot(e == ee);
    if (mask == 0ull) continue;
    int leader = __ffsll((unsigned long long)mask) - 1;
    int base = 0;
    if (lane == leader) base = atomicAdd(&cursor[ee], __popcll(mask));
    base = __shfl(base, leader);
    if (e == ee) slot = poff[ee] + base + __popcll(mask & lmask);
  }
  tok_list[slot] = tk >> 1;
  slot_of[tk] = slot;
}

// ---------------- combine: core = w0*e2[s0]+w1*e2[s1]; out = attn_x + LN(h+core)
__global__ void combine_kernel(const bf16* __restrict__ e2, const int* __restrict__ slot_of,
                               const float* __restrict__ rw, const float* __restrict__ hf,
                               const float* __restrict__ attn_x, const float* __restrict__ g,
                               const float* __restrict__ bb, float* __restrict__ out){
  int row = blockIdx.x, t = threadIdx.x;
  int sl0 = slot_of[row * 2], sl1 = slot_of[row * 2 + 1];
  float w0 = rw[row * 2], w1 = rw[row * 2 + 1];
  const bf16* r0 = e2 + (size_t)sl0 * ND;
  const bf16* r1 = e2 + (size_t)sl1 * ND;
  const float* hr = hf + (size_t)row * ND;
  float v[3]; float s = 0.f, sq = 0.f;
  #pragma unroll
  for (int i = 0; i < 3; i++){
    int idx = t + i * 256;
    float c = w0 * bf2f(r0[idx]) + w1 * bf2f(r1[idx]);
    float xv = hr[idx] + c;
    v[i] = xv; s += xv; sq += xv * xv;
  }
  __shared__ float rs[4], rq[4];
  #pragma unroll
  for (int d = 32; d >= 1; d >>= 1){ s += __shfl_xor(s, d); sq += __shfl_xor(sq, d); }
  int w = t >> 6;
  if ((t & 63) == 0){ rs[w] = s; rq[w] = sq; }
  __syncthreads();
  s = rs[0] + rs[1] + rs[2] + rs[3];
  sq = rq[0] + rq[1] + rq[2] + rq[3];
  float mean = s * (1.f / ND);
  float var = sq * (1.f / ND) - mean * mean;
  float rstd = rsqrtf(var + 1e-5f);
  #pragma unroll
  for (int i = 0; i < 3; i++){
    int idx = t + i * 256;
    float y = (v[i] - mean) * rstd * g[idx] + bb[idx];
    out[(size_t)row * ND + idx] = attn_x[(size_t)row * ND + idx] + y;
  }
}

// ================= host =================
extern "C" void kernel_launch(void* const* d_in, const int* in_sizes, int n_in,
                              void* d_out, int out_size, void* d_ws, size_t ws_size,
                              hipStream_t stream){
  const float* x        = (const float*)d_in[0];
  const float* ln_att_g = (const float*)d_in[2];
  const float* ln_att_b = (const float*)d_in[3];
  const float* wq = (const float*)d_in[4];  const float* bq = (const float*)d_in[5];
  const float* wk = (const float*)d_in[6];  const float* bk = (const float*)d_in[7];
  const float* wv = (const float*)d_in[8];  const float* bv = (const float*)d_in[9];
  const float* wo = (const float*)d_in[10]; const float* bo = (const float*)d_in[11];
  const float* ln_ff_g = (const float*)d_in[12];
  const float* ln_ff_b = (const float*)d_in[13];
  const float* gate_w  = (const float*)d_in[14];
  const float* gate_b  = (const float*)d_in[15];
  const float* w1 = (const float*)d_in[16]; const float* b1 = (const float*)d_in[17];
  const float* w2 = (const float*)d_in[18]; const float* b2 = (const float*)d_in[19];
  const float* moe_g = (const float*)d_in[20];
  const float* moe_b = (const float*)d_in[21];

  uint8_t* p = (uint8_t*)d_ws;
  auto alloc = [&](size_t bytes) -> void* {
    void* r = (void*)p;
    p += (bytes + 255) & ~(size_t)255;
    return r;
  };
  bf16* wqkv_t  = (bf16*)alloc((size_t)2304 * 768 * 2);
  bf16* wo_t    = (bf16*)alloc((size_t)768 * 768 * 2);
  bf16* w1_t    = (bf16*)alloc((size_t)NE * NHID * ND * 2);
  bf16* w2_t    = (bf16*)alloc((size_t)NE * ND * NHID * 2);
  float* bias_qkv = (float*)alloc(2304 * 4);
  bf16* a_bf    = (bf16*)alloc((size_t)NTOK * ND * 2);
  bf16* qkv     = (bf16*)alloc((size_t)NTOK * 2304 * 2);
  bf16* vT      = (bf16*)alloc((size_t)NB * NH * 64 * NS * 2);
  bf16* ctx     = (bf16*)alloc((size_t)NTOK * ND * 2);
  float* attn_x = (float*)alloc((size_t)NTOK * ND * 4);
  float* h_f    = (float*)alloc((size_t)NTOK * ND * 4);
  bf16* h_b     = (bf16*)alloc((size_t)NTOK * ND * 2);
  int*  ridx    = (int*)alloc(NASSIGN * 4);
  float* rwt    = (float*)alloc(NASSIGN * 4);
  int* counts   = (int*)alloc(NE * 4);
  int* poff     = (int*)alloc(NE * 4);
  int* cursor   = (int*)alloc(NE * 4);
  int* chunk_e  = (int*)alloc(MAXCH * 4);
  int* tok_list = (int*)alloc(MAXSLOT * 4);
  int* slot_of  = (int*)alloc(NASSIGN * 4);
  bf16* e1      = (bf16*)alloc((size_t)MAXSLOT * NHID * 2);
  bf16* e2      = (bf16*)alloc((size_t)MAXSLOT * ND * 2);

  hipMemsetAsync(counts, 0, NE * 4, stream);
  hipMemsetAsync(cursor, 0, NE * 4, stream);

  // weight prep
  transpose_convert_kernel<<<dim3(24, 24, 1), 256, 0, stream>>>(wq, wqkv_t, 768, 768);
  transpose_convert_kernel<<<dim3(24, 24, 1), 256, 0, stream>>>(wk, wqkv_t + (size_t)768 * 768, 768, 768);
  transpose_convert_kernel<<<dim3(24, 24, 1), 256, 0, stream>>>(wv, wqkv_t + (size_t)1536 * 768, 768, 768);
  transpose_convert_kernel<<<dim3(24, 24, 1), 256, 0, stream>>>(wo, wo_t, 768, 768);
  transpose_convert_kernel<<<dim3(96, 24, NE), 256, 0, stream>>>(w1, w1_t, 768, 3072);
  transpose_convert_kernel<<<dim3(24, 96, NE), 256, 0, stream>>>(w2, w2_t, 3072, 768);
  concat3_kernel<<<dim3(9), 256, 0, stream>>>(bq, bk, bv, bias_qkv);

  // attention path
  ln_kernel<false, true><<<dim3(NTOK), 256, 0, stream>>>(x, ln_att_g, ln_att_b, nullptr, a_bf);
  gemm_kernel<2, false, false, true, false, false><<<dim3(18, 16), 256, 0, stream>>>(
      a_bf, ND, wqkv_t, bias_qkv, qkv, 2304, nullptr, 2304, ND, nullptr, nullptr);
  vtrans_kernel<<<dim3(32, 2, NB * NH), 256, 0, stream>>>(qkv, vT);
  flash_attn_kernel<<<dim3(768), 256, 0, stream>>>(qkv, vT, ctx);
  gemm_kernel<1, false, false, false, true, false><<<dim3(6, 32), 256, 0, stream>>>(
      ctx, ND, wo_t, bo, attn_x, ND, x, ND, ND, nullptr, nullptr);

  // MoE path
  ln_kernel<true, true><<<dim3(NTOK), 256, 0, stream>>>(attn_x, ln_ff_g, ln_ff_b, h_f, h_b);
  gate_kernel<<<dim3(NTOK / 32), 256, 0, stream>>>(h_f, gate_w, gate_b, ridx, rwt, counts);
  scan_kernel<<<dim3(1), 256, 0, stream>>>(counts, poff, chunk_e, tok_list);
  scatter_kernel<<<dim3(NASSIGN / 256), 256, 0, stream>>>(ridx, poff, cursor, tok_list, slot_of);
  gemm_kernel<2, true, true, true, false, true><<<dim3(24, 36), 256, 0, stream>>>(
      h_b, ND, w1_t, b1, e1, NHID, nullptr, NHID, ND, chunk_e, tok_list);
  gemm_kernel<1, false, false, true, false, true><<<dim3(6, 72), 256, 0, stream>>>(
      e1, NHID, w2_t, b2, e2, ND, nullptr, ND, NHID, chunk_e, nullptr);
  combine_kernel<<<dim3(NTOK), 256, 0, stream>>>(e2, slot_of, rwt, h_f, attn_x, moe_g, moe_b,
                                                 (float*)d_out);
}